// Round 8
// baseline (1015.650 us; speedup 1.0000x reference)
//
#include <hip/hip_runtime.h>

#define D 256
#define T 4
#define NS 64

typedef unsigned int uint32;
typedef short s16x8 __attribute__((ext_vector_type(8)));
typedef float f32x4 __attribute__((ext_vector_type(4)));

// ---- bf16 helpers (manual RNE) --------------------------------------------
__device__ __forceinline__ float bflo(uint32 u) { return __uint_as_float(u << 16); }
__device__ __forceinline__ float bfhi(uint32 u) { return __uint_as_float(u & 0xffff0000u); }
__device__ __forceinline__ unsigned short f2bf(float x) {
    uint32 u = __float_as_uint(x);
    u = u + 0x7FFFu + ((u >> 16) & 1u);
    return (unsigned short)(u >> 16);
}
__device__ __forceinline__ uint32 pack2(float a, float b) {
    return (uint32)f2bf(a) | ((uint32)f2bf(b) << 16);
}
// relu on 2 packed bf16
__device__ __forceinline__ uint32 relu2(uint32 u) {
    uint32 s = u & 0x80008000u;
    uint32 m = ((s >> 15) ^ 0x00010001u) * 0xFFFFu;
    return u & m;
}

// ---------------------------------------------------------------------------
__global__ void zero_kernel(uint32* __restrict__ p, long long n)
{
    long long i = (long long)blockIdx.x * blockDim.x + threadIdx.x;
    long long st = (long long)gridDim.x * blockDim.x;
    for (; i < n; i += st) p[i] = 0u;
}

__global__ void f2bf_kernel(const float* __restrict__ in, unsigned short* __restrict__ out,
                            long long n8)
{
    long long i = (long long)blockIdx.x * blockDim.x + threadIdx.x;
    long long st = (long long)gridDim.x * blockDim.x;
    for (; i < n8; i += st) {
        float4 a = *(const float4*)(in + i * 8);
        float4 b = *(const float4*)(in + i * 8 + 4);
        uint4 o;
        o.x = pack2(a.x, a.y); o.y = pack2(a.z, a.w);
        o.z = pack2(b.x, b.y); o.w = pack2(b.z, b.w);
        *(uint4*)(out + i * 8) = o;
    }
}

// ---------------------------------------------------------------------------
// 6 weight matrices (gcn0, gcn1, lin_w[0..3]) fp32 256x256 -> B-frag-linear bf16
// ---------------------------------------------------------------------------
__global__ void wfrag_kernel(const float* __restrict__ g0, const float* __restrict__ g1,
                             const float* __restrict__ lw, unsigned short* __restrict__ out)
{
    int o = blockIdx.x * 256 + threadIdx.x;   // 0..65535
    int mat = blockIdx.y;
    const float* W = (mat == 0) ? g0 : (mat == 1) ? g1 : (lw + (size_t)(mat - 2) * 65536);
    int j = o & 7, lane = (o >> 3) & 63, ks = (o >> 9) & 7, nt = o >> 12;
    int n15 = lane & 15, quad = lane >> 4;
    int k = ks * 32 + quad * 8 + j;
    int n = nt * 16 + n15;
    out[(size_t)mat * 65536 + o] = f2bf(W[(size_t)k * 256 + n]);
}

// ---------------------------------------------------------------------------
// MFMA GEMM: C = A(bf16, Mx256) @ W(bf16 frag-linear) + bias.
// Output row for input row gr, batch z: gr*rowMul + z*zRowAdd
// (rowMul=1,zRowAdd=0: planar single; rowMul=T,zRowAdd=1: replica-interleaved)
// ---------------------------------------------------------------------------
__global__ __launch_bounds__(256, 2)
void gemm_mfma(const unsigned short* __restrict__ A,
               const unsigned short* __restrict__ Wfrag,
               const float* __restrict__ bias,
               unsigned short* __restrict__ Cout,
               int M, int nStripes, int rowMul, int zRowAdd)
{
    __shared__ unsigned short Asm[64 * 264];
    int t = threadIdx.x, w = t >> 6, lane = t & 63;
    int n15 = lane & 15, quad = lane >> 4;
    int z = blockIdx.y;
    Wfrag += (size_t)z * 65536;
    bias  += (size_t)z * 256;

    s16x8 bfr[4][8];
#pragma unroll
    for (int nt = 0; nt < 4; nt++)
#pragma unroll
        for (int ks = 0; ks < 8; ks++)
            bfr[nt][ks] = *(const s16x8*)(Wfrag +
                (size_t)(((w * 4 + nt) * 8 + ks) * 64 + lane) * 8);

    float bcol[4];
#pragma unroll
    for (int nt = 0; nt < 4; nt++) bcol[nt] = bias[(w * 4 + nt) * 16 + n15];

    for (int s = blockIdx.x; s < nStripes; s += gridDim.x) {
        int m0 = s * 64;
        __syncthreads();
#pragma unroll
        for (int i = 0; i < 8; i++) {
            int idx = i * 256 + t;
            int m = idx >> 5, kc = (idx & 31) * 8;
            int gm = m0 + m;
            uint4 v = make_uint4(0u, 0u, 0u, 0u);
            if (gm < M) v = *(const uint4*)(A + (size_t)gm * 256 + kc);
            *(uint4*)(Asm + m * 264 + kc) = v;
        }
        __syncthreads();

        f32x4 acc[4][4];
#pragma unroll
        for (int rt = 0; rt < 4; rt++)
#pragma unroll
            for (int nt = 0; nt < 4; nt++)
#pragma unroll
                for (int e = 0; e < 4; e++) acc[rt][nt][e] = 0.f;

#pragma unroll
        for (int rt = 0; rt < 4; rt++) {
            int abase = (rt * 16 + n15) * 264 + quad * 8;
#pragma unroll
            for (int ks = 0; ks < 8; ks++) {
                s16x8 a = *(const s16x8*)(Asm + abase + ks * 32);
#pragma unroll
                for (int nt = 0; nt < 4; nt++)
                    acc[rt][nt] = __builtin_amdgcn_mfma_f32_16x16x32_bf16(
                        a, bfr[nt][ks], acc[rt][nt], 0, 0, 0);
            }
        }

#pragma unroll
        for (int rt = 0; rt < 4; rt++) {
            int row0 = m0 + rt * 16 + quad * 4;
#pragma unroll
            for (int nt = 0; nt < 4; nt++) {
                int colp = (w * 4 + nt) * 16 + n15;
#pragma unroll
                for (int r = 0; r < 4; r++) {
                    int gr = row0 + r;
                    if (gr < M) {
                        size_t ro = (size_t)gr * rowMul + (size_t)z * zRowAdd;
                        Cout[ro * 256 + colp] = f2bf(acc[rt][nt][r] + bcol[nt]);
                    }
                }
            }
        }
    }
}

// ---------------------------------------------------------------------------
__global__ __launch_bounds__(256)
void tinv_kernel(const unsigned short* __restrict__ tr, float* __restrict__ tinv, int rows)
{
    int wave = threadIdx.x >> 6, lane = threadIdx.x & 63;
    int r = blockIdx.x * 4 + wave;
    if (r >= rows) return;
    uint2 q = *(const uint2*)(tr + (size_t)r * D + lane * 4);
    float a = bflo(q.x), b = bfhi(q.x), c = bflo(q.y), d = bfhi(q.y);
    float s = a * a + b * b + c * c + d * d;
#pragma unroll
    for (int off = 32; off; off >>= 1) s += __shfl_xor(s, off);
    if (lane == 0) tinv[r] = 1.f / fmaxf(sqrtf(s), 1e-8f);
}

// ---------------------------------------------------------------------------
// edge counting sort by dst; esorted = (src, dst) pairs in dst order
// ---------------------------------------------------------------------------
__global__ void ehist_kernel(const int* __restrict__ dst, int* __restrict__ ecnt, int E)
{
    for (int e = blockIdx.x * blockDim.x + threadIdx.x; e < E;
         e += gridDim.x * blockDim.x)
        atomicAdd(ecnt + dst[e], 1);
}

__global__ void escatter_kernel(const int* __restrict__ src, const int* __restrict__ dst,
                                const int* __restrict__ eptr, int* __restrict__ efill,
                                uint2* __restrict__ esorted, int E)
{
    for (int e = blockIdx.x * blockDim.x + threadIdx.x; e < E;
         e += gridDim.x * blockDim.x) {
        int d = dst[e];
        int pos = eptr[d] + atomicAdd(efill + d, 1);
        esorted[pos] = make_uint2((uint32)src[e], (uint32)d);
    }
}

// ---------------------------------------------------------------------------
// sim4: MFMA diagonal over 16 sorted edges/wave; trI is replica-INTERLEAVED
// (node-major: trI[(n*4+i)*D]) so each dst's 4 B-rows are 2KB contiguous.
// All 8 A-fragments preloaded for burst issue.
// ---------------------------------------------------------------------------
__global__ __launch_bounds__(256)
void sim4_kernel(const uint2* __restrict__ esorted,
                 const unsigned short* __restrict__ featb,
                 const unsigned short* __restrict__ trI, const float* __restrict__ tinv,
                 int* __restrict__ bestS, int E, int Nn)
{
    int w = threadIdx.x >> 6, lane = threadIdx.x & 63;
    int n15 = lane & 15, quad = lane >> 4;
    int base = (blockIdx.x * 4 + w) * 16;
    if (base >= E) return;
    int ei = min(base + n15, E - 1);
    uint2 se = esorted[ei];
    const unsigned short* arow = featb + (size_t)se.x * D + quad * 8;
    const unsigned short* brow = trI + ((size_t)se.y * 4) * D + quad * 8;

    s16x8 a[8];
#pragma unroll
    for (int ks = 0; ks < 8; ks++) a[ks] = *(const s16x8*)(arow + ks * 32);

    f32x4 a0 = {0.f, 0.f, 0.f, 0.f}, a1 = a0, a2 = a0, a3 = a0;
#pragma unroll
    for (int ks = 0; ks < 8; ks++) {
        s16x8 b0 = *(const s16x8*)(brow + ks * 32);
        a0 = __builtin_amdgcn_mfma_f32_16x16x32_bf16(a[ks], b0, a0, 0, 0, 0);
    }
#pragma unroll
    for (int ks = 0; ks < 8; ks++) {
        s16x8 b1 = *(const s16x8*)(brow + D + ks * 32);
        a1 = __builtin_amdgcn_mfma_f32_16x16x32_bf16(a[ks], b1, a1, 0, 0, 0);
    }
#pragma unroll
    for (int ks = 0; ks < 8; ks++) {
        s16x8 b2 = *(const s16x8*)(brow + 2 * D + ks * 32);
        a2 = __builtin_amdgcn_mfma_f32_16x16x32_bf16(a[ks], b2, a2, 0, 0, 0);
    }
#pragma unroll
    for (int ks = 0; ks < 8; ks++) {
        s16x8 b3 = *(const s16x8*)(brow + 3 * D + ks * 32);
        a3 = __builtin_amdgcn_mfma_f32_16x16x32_bf16(a[ks], b3, a3, 0, 0, 0);
    }

    if (quad == (n15 >> 2) && base + n15 < E) {
        int r = n15 & 3;
        int d4 = (int)se.y * 4;
        float v0 = a0[r] * tinv[d4];
        float v1 = a1[r] * tinv[d4 + 1];
        float v2 = a2[r] * tinv[d4 + 2];
        float v3 = a3[r] * tinv[d4 + 3];
        float bv = v0; int bi = 0;
        if (v1 > bv) { bv = v1; bi = 1; }   // strict >: first-index ties
        if (v2 > bv) { bv = v2; bi = 2; }
        if (v3 > bv) { bv = v3; bi = 3; }
        bestS[base + n15] = bi;
    }
}

// ---------------------------------------------------------------------------
// unified edge list over SORTED edges (degree histogram only)
// ---------------------------------------------------------------------------
__device__ __forceinline__ void decode_edge(int e, const uint2* __restrict__ esorted,
                                            const int* __restrict__ bestS,
                                            int E, int Nn, int& s, int& d, bool& keep)
{
    if (e < E) {
        uint2 se = esorted[e];
        s = (int)se.x; d = (int)se.y; keep = (s != d);
    } else if (e < 2 * E) {
        int k = e - E;
        uint2 se = esorted[k];
        s = (int)se.x; d = (int)se.y + bestS[k] * Nn; keep = (s != d);
    } else if (e < 2 * E + T * Nn) {
        int k = e - 2 * E; int i = k / Nn; int n = k - i * Nn;
        s = n; d = n + i * Nn; keep = (i != 0);
    } else {
        int v = e - (2 * E + T * Nn); s = v; d = v; keep = true;
    }
}

__global__ void hist_kernel(const uint2* __restrict__ esorted, const int* __restrict__ bestS,
                            int* __restrict__ cnt, int E, int Nn)
{
    int total = 2 * E + (2 * T + 1) * Nn;
    for (int e = blockIdx.x * blockDim.x + threadIdx.x; e < total;
         e += gridDim.x * blockDim.x) {
        int s, d; bool keep;
        decode_edge(e, esorted, bestS, E, Nn, s, d, keep);
        if (keep) atomicAdd(cnt + d, 1);
    }
}

__global__ void dinv_kernel(const int* __restrict__ cnt, float* __restrict__ dinv, int n)
{
    int v = blockIdx.x * blockDim.x + threadIdx.x;
    if (v < n) dinv[v] = (cnt[v] > 0) ? rsqrtf((float)cnt[v]) : 0.f;
}

// per-edge packed meta in sorted order: (src | best<<27, dinv[src])
__global__ void emeta_kernel(const uint2* __restrict__ esorted, const int* __restrict__ bestS,
                             const float* __restrict__ dinv, uint2* __restrict__ emeta, int E)
{
    for (int e = blockIdx.x * blockDim.x + threadIdx.x; e < E;
         e += gridDim.x * blockDim.x) {
        uint2 se = esorted[e];
        uint32 packed = se.x | ((uint32)bestS[e] << 27);
        emeta[e] = make_uint2(packed, __float_as_uint(dinv[se.x]));
    }
}

__global__ void scan_sums(const int* __restrict__ cnt, int* __restrict__ aux, int n)
{
    __shared__ int sd[256];
    int idx = blockIdx.x * 256 + threadIdx.x;
    sd[threadIdx.x] = (idx < n) ? cnt[idx] : 0;
    __syncthreads();
    for (int off = 128; off; off >>= 1) {
        if (threadIdx.x < off) sd[threadIdx.x] += sd[threadIdx.x + off];
        __syncthreads();
    }
    if (threadIdx.x == 0) aux[blockIdx.x] = sd[0];
}

__global__ void scan_aux(const int* __restrict__ aux, int* __restrict__ auxex, int nb)
{
    __shared__ int sd[1024];
    int t = threadIdx.x;
    int v = (t < nb) ? aux[t] : 0;
    sd[t] = v;
    __syncthreads();
    for (int off = 1; off < 1024; off <<= 1) {
        int x = (t >= off) ? sd[t - off] : 0;
        __syncthreads();
        sd[t] += x;
        __syncthreads();
    }
    if (t < nb) auxex[t] = sd[t] - v;
}

__global__ void scan_write(const int* __restrict__ cnt, const int* __restrict__ auxex,
                           int* __restrict__ rowptr, int n)
{
    __shared__ int sd[256];
    int t = threadIdx.x;
    int idx = blockIdx.x * 256 + t;
    int v = (idx < n) ? cnt[idx] : 0;
    sd[t] = v;
    __syncthreads();
    for (int off = 1; off < 256; off <<= 1) {
        int x = (t >= off) ? sd[t - off] : 0;
        __syncthreads();
        sd[t] += x;
        __syncthreads();
    }
    if (idx < n) {
        int rp = auxex[blockIdx.x] + sd[t] - v;
        rowptr[idx] = rp;
        if (idx == n - 1) rowptr[n] = rp + v;
    }
}

// ---------------------------------------------------------------------------
// agg5: one wave per BASE node v, produces all 5 output rows {v, v+iN}.
// xb replica row for node v, replica i: v*xrm + i*xra
// (interleaved trI: xrm=4,xra=1; planar R1 replicas: xrm=1,xra=Nn)
// ---------------------------------------------------------------------------
__global__ __launch_bounds__(256)
void agg5_kernel(const int* __restrict__ eptr, const uint2* __restrict__ emeta,
                 const unsigned short* __restrict__ xa,
                 const unsigned short* __restrict__ xb,
                 const float* __restrict__ dinv,
                 unsigned short* __restrict__ outb, int Nn, int xrm, int xra)
{
    int wave = threadIdx.x >> 6, lane = threadIdx.x & 63;
    int v = blockIdx.x * 4 + wave;
    if (v >= Nn) return;

    float dv  = dinv[v];
    float dr1 = dinv[v + Nn];
    float dr2 = dinv[v + 2 * Nn];
    float dr3 = dinv[v + 3 * Nn];
    float dr4 = dinv[v + 4 * Nn];

    uint2 qv = *(const uint2*)(xa + (size_t)v * D + lane * 4);
    qv.x = relu2(qv.x); qv.y = relu2(qv.y);
    float y0 = bflo(qv.x), y1 = bfhi(qv.x), y2 = bflo(qv.y), y3 = bfhi(qv.y);

    float wsb = dv * dv;
    float b0 = wsb * y0, b1 = wsb * y1, b2 = wsb * y2, b3 = wsb * y3;

    float wi1 = dv * dr1, wi2 = dv * dr2, wi3 = dv * dr3;
    float r10 = wi1 * y0, r11 = wi1 * y1, r12 = wi1 * y2, r13 = wi1 * y3;
    float r20 = wi2 * y0, r21 = wi2 * y1, r22 = wi2 * y2, r23 = wi2 * y3;
    float r30 = wi3 * y0, r31 = wi3 * y1, r32 = wi3 * y2, r33 = wi3 * y3;
    float r40 = 0.f, r41 = 0.f, r42 = 0.f, r43 = 0.f;

    {
        uint2 q = *(const uint2*)(xb + ((size_t)v * xrm + 0 * (size_t)xra) * D + lane * 4);
        q.x = relu2(q.x); q.y = relu2(q.y);
        float ws = dr1 * dr1;
        r10 = fmaf(ws, bflo(q.x), r10); r11 = fmaf(ws, bfhi(q.x), r11);
        r12 = fmaf(ws, bflo(q.y), r12); r13 = fmaf(ws, bfhi(q.y), r13);
    }
    {
        uint2 q = *(const uint2*)(xb + ((size_t)v * xrm + 1 * (size_t)xra) * D + lane * 4);
        q.x = relu2(q.x); q.y = relu2(q.y);
        float ws = dr2 * dr2;
        r20 = fmaf(ws, bflo(q.x), r20); r21 = fmaf(ws, bfhi(q.x), r21);
        r22 = fmaf(ws, bflo(q.y), r22); r23 = fmaf(ws, bfhi(q.y), r23);
    }
    {
        uint2 q = *(const uint2*)(xb + ((size_t)v * xrm + 2 * (size_t)xra) * D + lane * 4);
        q.x = relu2(q.x); q.y = relu2(q.y);
        float ws = dr3 * dr3;
        r30 = fmaf(ws, bflo(q.x), r30); r31 = fmaf(ws, bfhi(q.x), r31);
        r32 = fmaf(ws, bflo(q.y), r32); r33 = fmaf(ws, bfhi(q.y), r33);
    }
    {
        uint2 q = *(const uint2*)(xb + ((size_t)v * xrm + 3 * (size_t)xra) * D + lane * 4);
        q.x = relu2(q.x); q.y = relu2(q.y);
        float ws = dr4 * dr4;
        r40 = fmaf(ws, bflo(q.x), r40); r41 = fmaf(ws, bfhi(q.x), r41);
        r42 = fmaf(ws, bflo(q.y), r42); r43 = fmaf(ws, bfhi(q.y), r43);
    }

    int j = eptr[v], jend = eptr[v + 1];

#define EDGE_BODY(qq, ss, bb, ww)                                                  \
    {                                                                              \
        float x0 = bflo(qq.x), x1 = bfhi(qq.x), x2 = bflo(qq.y), x3 = bfhi(qq.y);  \
        float wb = (ss != v) ? (ww) * dv : 0.f;                                    \
        if (bb == 0) wb += wb;                                                     \
        b0 = fmaf(wb, x0, b0); b1 = fmaf(wb, x1, b1);                              \
        b2 = fmaf(wb, x2, b2); b3 = fmaf(wb, x3, b3);                              \
        if (bb == 1) {                                                             \
            float wr = (ww) * dr1;                                                 \
            r10 = fmaf(wr, x0, r10); r11 = fmaf(wr, x1, r11);                      \
            r12 = fmaf(wr, x2, r12); r13 = fmaf(wr, x3, r13);                      \
        } else if (bb == 2) {                                                      \
            float wr = (ww) * dr2;                                                 \
            r20 = fmaf(wr, x0, r20); r21 = fmaf(wr, x1, r21);                      \
            r22 = fmaf(wr, x2, r22); r23 = fmaf(wr, x3, r23);                      \
        } else if (bb == 3) {                                                      \
            float wr = (ww) * dr3;                                                 \
            r30 = fmaf(wr, x0, r30); r31 = fmaf(wr, x1, r31);                      \
            r32 = fmaf(wr, x2, r32); r33 = fmaf(wr, x3, r33);                      \
        }                                                                          \
    }

    for (; j + 2 <= jend; j += 2) {
        uint2 m0 = emeta[j];
        uint2 m1 = emeta[j + 1];
        uint32 su0 = (uint32)__builtin_amdgcn_readfirstlane((int)m0.x);
        uint32 su1 = (uint32)__builtin_amdgcn_readfirstlane((int)m1.x);
        float ws0 = __uint_as_float((uint32)__builtin_amdgcn_readfirstlane((int)m0.y));
        float ws1 = __uint_as_float((uint32)__builtin_amdgcn_readfirstlane((int)m1.y));
        int s0 = (int)(su0 & 0x07FFFFFFu), bx0 = (int)(su0 >> 27);
        int s1 = (int)(su1 & 0x07FFFFFFu), bx1 = (int)(su1 >> 27);
        uint2 q0 = *(const uint2*)(xa + (size_t)s0 * D + lane * 4);
        uint2 q1 = *(const uint2*)(xa + (size_t)s1 * D + lane * 4);
        q0.x = relu2(q0.x); q0.y = relu2(q0.y);
        q1.x = relu2(q1.x); q1.y = relu2(q1.y);
        EDGE_BODY(q0, s0, bx0, ws0);
        EDGE_BODY(q1, s1, bx1, ws1);
    }
    if (j < jend) {
        uint2 m0 = emeta[j];
        uint32 su0 = (uint32)__builtin_amdgcn_readfirstlane((int)m0.x);
        float ws0 = __uint_as_float((uint32)__builtin_amdgcn_readfirstlane((int)m0.y));
        int s0 = (int)(su0 & 0x07FFFFFFu), bx0 = (int)(su0 >> 27);
        uint2 q0 = *(const uint2*)(xa + (size_t)s0 * D + lane * 4);
        q0.x = relu2(q0.x); q0.y = relu2(q0.y);
        EDGE_BODY(q0, s0, bx0, ws0);
    }
#undef EDGE_BODY

    uint2 o;
    o.x = pack2(b0, b1); o.y = pack2(b2, b3);
    *(uint2*)(outb + (size_t)v * D + lane * 4) = o;
    o.x = pack2(r10, r11); o.y = pack2(r12, r13);
    *(uint2*)(outb + ((size_t)v + Nn) * D + lane * 4) = o;
    o.x = pack2(r20, r21); o.y = pack2(r22, r23);
    *(uint2*)(outb + ((size_t)v + 2 * (size_t)Nn) * D + lane * 4) = o;
    o.x = pack2(r30, r31); o.y = pack2(r32, r33);
    *(uint2*)(outb + ((size_t)v + 3 * (size_t)Nn) * D + lane * 4) = o;
    o.x = pack2(r40, r41); o.y = pack2(r42, r43);
    *(uint2*)(outb + ((size_t)v + 4 * (size_t)Nn) * D + lane * 4) = o;
}

// ---------------------------------------------------------------------------
// MFMA logits + fused argmax + H
// ---------------------------------------------------------------------------
__global__ __launch_bounds__(256, 2)
void logits_mfma(const unsigned short* __restrict__ af2, const float* __restrict__ Wl,
                 const float* __restrict__ bl, float* __restrict__ H,
                 int M, int Nn, int nStripes)
{
    __shared__ unsigned short Asm[64 * 264];
    int t = threadIdx.x, w = t >> 6, lane = t & 63;
    int n15 = lane & 15, quad = lane >> 4;

    s16x8 bfr[4][8];
#pragma unroll
    for (int nt = 0; nt < 4; nt++)
#pragma unroll
        for (int ks = 0; ks < 8; ks++) {
            s16x8 f;
#pragma unroll
            for (int j = 0; j < 8; j++) {
                int k = ks * 32 + quad * 8 + j;
                f[j] = (short)f2bf(Wl[(size_t)k * NS + nt * 16 + n15]);
            }
            bfr[nt][ks] = f;
        }
    float bcol[4];
#pragma unroll
    for (int nt = 0; nt < 4; nt++) bcol[nt] = bl[nt * 16 + n15];

    for (int s = blockIdx.x; s < nStripes; s += gridDim.x) {
        int m0 = s * 64;
        __syncthreads();
#pragma unroll
        for (int i = 0; i < 8; i++) {
            int idx = i * 256 + t;
            int m = idx >> 5, kc = (idx & 31) * 8;
            int gm = m0 + m;
            uint4 v = make_uint4(0u, 0u, 0u, 0u);
            if (gm < M) {
                v = *(const uint4*)(af2 + (size_t)gm * 256 + kc);
                v.x = relu2(v.x); v.y = relu2(v.y);
                v.z = relu2(v.z); v.w = relu2(v.w);
            }
            *(uint4*)(Asm + m * 264 + kc) = v;
        }
        __syncthreads();

        f32x4 acc[4];
#pragma unroll
        for (int nt = 0; nt < 4; nt++)
#pragma unroll
            for (int e = 0; e < 4; e++) acc[nt][e] = 0.f;

        int abase = (w * 16 + n15) * 264 + quad * 8;
#pragma unroll
        for (int ks = 0; ks < 8; ks++) {
            s16x8 a = *(const s16x8*)(Asm + abase + ks * 32);
#pragma unroll
            for (int nt = 0; nt < 4; nt++)
                acc[nt] = __builtin_amdgcn_mfma_f32_16x16x32_bf16(
                    a, bfr[nt][ks], acc[nt], 0, 0, 0);
        }

#pragma unroll
        for (int e = 0; e < 4; e++) {
            float bv = acc[0][e] + bcol[0]; int bi = n15;
#pragma unroll
            for (int nt = 1; nt < 4; nt++) {
                float v = acc[nt][e] + bcol[nt];
                int c = nt * 16 + n15;
                if (v > bv) { bv = v; bi = c; }
            }
#pragma unroll
            for (int off = 1; off < 16; off <<= 1) {
                float ov = __shfl_xor(bv, off);
                int   oi = __shfl_xor(bi, off);
                if (ov > bv || (ov == bv && oi < bi)) { bv = ov; bi = oi; }
            }
            if (n15 == 0) {
                int gr = m0 + w * 16 + quad * 4 + e;
                if (gr < M) atomicAdd(H + (size_t)(gr % Nn) * NS + bi, 1.0f);
            }
        }
    }
}

// ---------------------------------------------------------------------------
// maskTb: H (Nn x NS fp32) -> bf16 maskT [NS][Kpad] (1.0 where H>0, else 0),
// zero-padded in [Nn, Kpad). LDS-tiled transpose, coalesced both sides.
// ---------------------------------------------------------------------------
__global__ __launch_bounds__(256)
void maskTb_kernel(const float* __restrict__ H, unsigned short* __restrict__ maskTb,
                   int Nn, int Kpad)
{
    __shared__ unsigned short tile[64 * 72];   // [c][n], pad 72
    int t = threadIdx.x;
    int n0 = blockIdx.x * 64;
    int c = t & 63, rr = t >> 6;
#pragma unroll
    for (int i = 0; i < 16; i++) {
        int n = rr + i * 4;
        float hv = (n0 + n < Nn) ? H[(size_t)(n0 + n) * NS + c] : 0.f;
        tile[c * 72 + n] = (hv > 0.f) ? (unsigned short)0x3F80 : (unsigned short)0;
    }
    __syncthreads();
#pragma unroll
    for (int i = 0; i < 2; i++) {
        int idx = i * 256 + t;              // 0..511: 64 rows x 8 chunks
        int cc = idx >> 3, ch = idx & 7;
        uint4 v = *(const uint4*)(tile + cc * 72 + ch * 8);
        *(uint4*)(maskTb + (size_t)cc * Kpad + n0 + ch * 8) = v;
    }
}

// ---------------------------------------------------------------------------
// he_gemm: he = maskTb (64 x Kpad bf16) @ af2 (Kpad x 256 bf16), split-K.
// ---------------------------------------------------------------------------
__global__ __launch_bounds__(256, 2)
void he_gemm(const unsigned short* __restrict__ maskTb,
             const unsigned short* __restrict__ af2,
             float* __restrict__ partials, int Kpad)
{
    __shared__ unsigned short Bsm[32 * 264];
    int t = threadIdx.x, w = t >> 6, lane = t & 63;
    int n15 = lane & 15, quad = lane >> 4;
    int k0 = blockIdx.x * 256;

    f32x4 acc[4][4];
#pragma unroll
    for (int mt = 0; mt < 4; mt++)
#pragma unroll
        for (int nt = 0; nt < 4; nt++)
#pragma unroll
            for (int e = 0; e < 4; e++) acc[mt][nt][e] = 0.f;

    for (int s = 0; s < 8; s++) {
        int k = k0 + s * 32;
        __syncthreads();
#pragma unroll
        for (int i = 0; i < 4; i++) {
            int idx = i * 256 + t;              // 0..1023: 32 rows x 32 chunks
            int row = idx >> 5, col8 = (idx & 31) * 8;
            uint4 v = *(const uint4*)(af2 + (size_t)(k + row) * 256 + col8);
            *(uint4*)(Bsm + row * 264 + col8) = v;
        }
        __syncthreads();

        s16x8 a[4];
#pragma unroll
        for (int mt = 0; mt < 4; mt++)
            a[mt] = *(const s16x8*)(maskTb + (size_t)(mt * 16 + n15) * Kpad
                                    + k + quad * 8);
#pragma unroll
        for (int nt = 0; nt < 4; nt++) {
            int ncol = w * 64 + nt * 16 + n15;
            s16x8 b;
#pragma unroll
            for (int j = 0; j < 8; j++)
                b[j] = (short)Bsm[(quad * 8 + j) * 264 + ncol];
#pragma unroll
            for (int mt = 0; mt < 4; mt++)
                acc[mt][nt] = __builtin_amdgcn_mfma_f32_16x16x32_bf16(
                    a[mt], b, acc[mt][nt], 0, 0, 0);
        }
    }

    float* pdst = partials + (size_t)blockIdx.x * (64 * 256);
#pragma unroll
    for (int mt = 0; mt < 4; mt++)
#pragma unroll
        for (int nt = 0; nt < 4; nt++)
#pragma unroll
            for (int r = 0; r < 4; r++) {
                int m = mt * 16 + quad * 4 + r;
                int n = w * 64 + nt * 16 + n15;
                pdst[(size_t)m * 256 + n] = acc[mt][nt][r];
            }
}

// ---------------------------------------------------------------------------
// he_reduce2: out_he[c][f] = sum_b partials[b][c][f]  (plain store)
// ---------------------------------------------------------------------------
__global__ __launch_bounds__(256)
void he_reduce2(const float* __restrict__ partials, float* __restrict__ he, int KB)
{
    int idx = blockIdx.x * 256 + threadIdx.x;   // 0..16383
    float s = 0.f;
    for (int b = 0; b < KB; b++)
        s += partials[(size_t)b * 16384 + idx];
    he[idx] = s;
}

// ---------------------------------------------------------------------------
__global__ void bigb_copy(const float* __restrict__ he, float* __restrict__ BigB)
{
    int idx = blockIdx.x * 256 + threadIdx.x;
    if (idx < D * NS) {
        int d = idx >> 6, c = idx & 63;
        BigB[idx] = he[(size_t)c * D + d];
    }
}

__global__ __launch_bounds__(256)
void bigb_mm(const float* __restrict__ lin_w, const float* __restrict__ lin_b,
             const float* __restrict__ he, float* __restrict__ BigB,
             float* __restrict__ beta)
{
    int gw = (int)((blockIdx.x * 256 + threadIdx.x) >> 6);
    int lane = threadIdx.x & 63;
    const int totalA = T * D * NS;
    if (gw >= totalA + T * NS) return;
    const float* xrow; const float* hrow; float* outp;
    if (gw < totalA) {
        int t = gw / (D * NS); int rem = gw - t * D * NS;
        int d = rem / NS; int c = rem - d * NS;
        xrow = lin_w + ((size_t)t * D + d) * D;
        hrow = he + (size_t)c * D;
        outp = BigB + ((size_t)(t + 1) * D + d) * NS + c;
    } else {
        int i = gw - totalA; int t = i / NS; int c = i - t * NS;
        xrow = lin_b + (size_t)t * D;
        hrow = he + (size_t)c * D;
        outp = beta + (size_t)(t + 1) * NS + c;
    }
    float4 x = *(const float4*)(xrow + lane * 4);
    float4 h = *(const float4*)(hrow + lane * 4);
    float s = x.x * h.x + x.y * h.y + x.z * h.z + x.w * h.w;
#pragma unroll
    for (int off = 32; off; off >>= 1) s += __shfl_xor(s, off);
    if (lane == 0) *outp = s;
}

// ---------------------------------------------------------------------------
// MFMA dots: A-rows from featb (bf16, useBf=1, must NOT alias dots) or
// staged fp32 feat (useBf=0). grid (nBlk, 5)
// ---------------------------------------------------------------------------
__global__ __launch_bounds__(256, 2)
void dots_mfma(const unsigned short* __restrict__ featb,
               const float* __restrict__ feat32, int useBf,
               const float* __restrict__ BigB,
               const float* __restrict__ beta, float* __restrict__ dots,
               int Nn, int nStripes)
{
    __shared__ unsigned short Asm[64 * 264];
    int t = threadIdx.x, w = t >> 6, lane = t & 63;
    int n15 = lane & 15, quad = lane >> 4;
    int rho = blockIdx.y;
    const float* Bp = BigB + (size_t)rho * D * NS;

    s16x8 bfr[4][8];
#pragma unroll
    for (int nt = 0; nt < 4; nt++)
#pragma unroll
        for (int ks = 0; ks < 8; ks++) {
            s16x8 f;
#pragma unroll
            for (int j = 0; j < 8; j++) {
                int k = ks * 32 + quad * 8 + j;
                f[j] = (short)f2bf(Bp[(size_t)k * NS + nt * 16 + n15]);
            }
            bfr[nt][ks] = f;
        }
    float bcol[4];
#pragma unroll
    for (int nt = 0; nt < 4; nt++) bcol[nt] = beta[rho * NS + nt * 16 + n15];

    for (int s = blockIdx.x; s < nStripes; s += gridDim.x) {
        int m0 = s * 64;
        __syncthreads();
#pragma unroll
        for (int i = 0; i < 8; i++) {
            int idx = i * 256 + t;
            int m = idx >> 5, kc = (idx & 31) * 8;
            int gm = m0 + m;
            uint4 o = make_uint4(0u, 0u, 0u, 0u);
            if (gm < Nn) {
                if (useBf) {
                    o = *(const uint4*)(featb + (size_t)gm * 256 + kc);
                } else {
                    float4 a = *(const float4*)(feat32 + (size_t)gm * 256 + kc);
                    float4 b = *(const float4*)(feat32 + (size_t)gm * 256 + kc + 4);
                    o.x = pack2(a.x, a.y); o.y = pack2(a.z, a.w);
                    o.z = pack2(b.x, b.y); o.w = pack2(b.z, b.w);
                }
            }
            *(uint4*)(Asm + m * 264 + kc) = o;
        }
        __syncthreads();

        f32x4 acc[4];
#pragma unroll
        for (int nt = 0; nt < 4; nt++)
#pragma unroll
            for (int e = 0; e < 4; e++) acc[nt][e] = 0.f;

        int abase = (w * 16 + n15) * 264 + quad * 8;
#pragma unroll
        for (int ks = 0; ks < 8; ks++) {
            s16x8 a = *(const s16x8*)(Asm + abase + ks * 32);
#pragma unroll
            for (int nt = 0; nt < 4; nt++)
                acc[nt] = __builtin_amdgcn_mfma_f32_16x16x32_bf16(
                    a, bfr[nt][ks], acc[nt], 0, 0, 0);
        }

#pragma unroll
        for (int e = 0; e < 4; e++) {
            int gr = m0 + w * 16 + quad * 4 + e;
            if (gr >= Nn) continue;
#pragma unroll
            for (int nt = 0; nt < 4; nt++) {
                int c = nt * 16 + n15;
                dots[((size_t)rho * Nn + gr) * NS + c] = (acc[nt][e] + bcol[nt]) * 0.0625f;
            }
        }
    }
}

// ---------------------------------------------------------------------------
extern "C" void kernel_launch(void* const* d_in, const int* in_sizes, int n_in,
                              void* d_out, int out_size, void* d_ws, size_t ws_size,
                              hipStream_t stream)
{
    const int*   edge_index = (const int*)d_in[0];
    const float* features   = (const float*)d_in[1];
    const float* lin_w      = (const float*)d_in[2];
    const float* lin_b      = (const float*)d_in[3];
    const float* gcn0_w     = (const float*)d_in[4];
    const float* gcn0_b     = (const float*)d_in[5];
    const float* gcn1_w     = (const float*)d_in[6];
    const float* gcn1_b     = (const float*)d_in[7];
    const float* lin1_w     = (const float*)d_in[8];
    const float* lin1_b     = (const float*)d_in[9];

    int E  = in_sizes[0] / 2;
    int Nn = in_sizes[1] / D;
    int n_total = (T + 1) * Nn;
    int Mrep = T * Nn;

    const int* src = edge_index;
    const int* dst = edge_index + E;

    float* out_H    = (float*)d_out;
    float* out_he   = out_H + (size_t)Nn * NS;
    float* out_dots = out_he + (size_t)NS * D;

    // he GEMM split-K geometry
    int KB   = (Nn + 255) / 256;      // blocks, 256 K per block
    int Kpad = KB * 256;

    // ---- ws carve: two big bf16 regions + BigB (+ featb if it fits)
    char* ws0 = (char*)d_ws;
    char* wsp = ws0;
    auto carve = [&](size_t bytes) {
        char* p = wsp; wsp += (bytes + 255) & ~(size_t)255; return p;
    };
    unsigned short* R1   = (unsigned short*)carve((size_t)n_total * D * 2);
    unsigned short* R2   = (unsigned short*)carve((size_t)n_total * D * 2);
    float*          BigB = (float*)carve((size_t)(T + 1) * D * NS * 4);
    float*          beta = (float*)carve((size_t)(T + 1) * NS * 4);
    unsigned short* trI  = R2;   // prefix of R2, replica-INTERLEAVED transformed

    // featb: prefer ws (safe to read during dots_mfma); fall back to the
    // out_dots scratch region + fp32 staging in dots_mfma.
    size_t featb_bytes = (size_t)Nn * D * 2;
    unsigned short* featb = nullptr;
    int useBfDots = 0;
    if ((size_t)(wsp - ws0) + featb_bytes + 256 <= ws_size) {
        featb = (unsigned short*)carve(featb_bytes);
        useBfDots = 1;
    }

    // ---- scratch in the out_dots region (dead before dots_mfma)
    char* sc = (char*)out_dots;
    auto carve2 = [&](size_t bytes) {
        char* p = sc; sc += (bytes + 255) & ~(size_t)255; return p;
    };
    float* tinv    = (float*)carve2((size_t)Mrep * 4);
    int*   best    = (int*)carve2((size_t)E * 4);       // SORTED order
    int*   cnt     = (int*)carve2((size_t)n_total * 4);
    float* dinv    = (float*)carve2((size_t)n_total * 4);
    int*   aux     = (int*)carve2(1024 * 4);
    int*   auxex   = (int*)carve2(1024 * 4);
    if (!featb) featb = (unsigned short*)carve2(featb_bytes);
    unsigned short* Wfrags = (unsigned short*)carve2((size_t)6 * 65536 * 2);
    int*   ecnt    = (int*)carve2((size_t)Nn * 4);
    int*   eptr    = (int*)carve2((size_t)(Nn + 1) * 4);
    int*   efill   = (int*)carve2((size_t)Nn * 4);
    uint2* esorted = (uint2*)carve2((size_t)E * 8);     // (src, dst) in dst order
    uint2* emeta   = (uint2*)carve2((size_t)E * 8);     // (src|best<<27, dinv[src])
    unsigned short* maskTb = (unsigned short*)carve2((size_t)NS * Kpad * 2);

    // he_gemm partials live in R1 (dead after layer-1 agg): KB*64KB ~ 12.8MB
    float* partials = (float*)R1;

    // ---- zero accumulators
    zero_kernel<<<512, 256, 0, stream>>>((uint32*)cnt, n_total);
    zero_kernel<<<512, 256, 0, stream>>>((uint32*)ecnt, Nn);
    zero_kernel<<<512, 256, 0, stream>>>((uint32*)efill, Nn);
    zero_kernel<<<512, 256, 0, stream>>>((uint32*)out_H, (long long)Nn * NS + NS * D);
    zero_kernel<<<1, 256, 0, stream>>>((uint32*)beta, (T + 1) * NS);

    // 0. conversions
    wfrag_kernel<<<dim3(256, 6), 256, 0, stream>>>(gcn0_w, gcn1_w, lin_w, Wfrags);
    f2bf_kernel<<<2048, 256, 0, stream>>>(features, featb, (long long)Nn * D / 8);

    // 1. trI[(n*4+z)] = featb[n] @ lin_w[z] + lin_b[z]  (replica-interleaved)
    int strN = (Nn + 63) / 64;
    gemm_mfma<<<dim3(512, T), 256, 0, stream>>>(featb, Wfrags + 2 * 65536, lin_b,
                                                trI, Nn, strN, T, 1);
    // 2. row norms (trI rows: node n replica i at n*4+i)
    tinv_kernel<<<(Mrep + 3) / 4, 256, 0, stream>>>(trI, tinv, Mrep);

    // 3. edge sort by dst + MFMA-diagonal sim
    ehist_kernel<<<2048, 256, 0, stream>>>(dst, ecnt, E);
    int enb = (Nn + 255) / 256;
    scan_sums<<<enb, 256, 0, stream>>>(ecnt, aux, Nn);
    scan_aux<<<1, 1024, 0, stream>>>(aux, auxex, enb);
    scan_write<<<enb, 256, 0, stream>>>(ecnt, auxex, eptr, Nn);
    escatter_kernel<<<2048, 256, 0, stream>>>(src, dst, eptr, efill, esorted, E);
    int nGroups = (E + 15) / 16;
    sim4_kernel<<<(nGroups + 3) / 4, 256, 0, stream>>>(esorted, featb, trI,
                                                       tinv, best, E, Nn);

    // 4. degrees -> dinv -> packed per-edge meta
    hist_kernel<<<2048, 256, 0, stream>>>(esorted, best, cnt, E, Nn);
    dinv_kernel<<<(n_total + 255) / 256, 256, 0, stream>>>(cnt, dinv, n_total);
    emeta_kernel<<<2048, 256, 0, stream>>>(esorted, best, dinv, emeta, E);

    // 5. layer 0 (xb = trI, interleaved rows v*4+i)
    int strT = (n_total + 63) / 64;
    agg5_kernel<<<(Nn + 3) / 4, 256, 0, stream>>>(eptr, emeta, featb, trI,
                                                  dinv, R1, Nn, 4, 1);
    gemm_mfma<<<dim3(512, 1), 256, 0, stream>>>(R1, Wfrags, gcn0_b, R1, n_total,
                                                strT, 1, 0);

    // 6. layer 1 (xb = R1 planar replicas, rows v + i*Nn)
    agg5_kernel<<<(Nn + 3) / 4, 256, 0, stream>>>(eptr, emeta, R1, R1 + (size_t)Nn * D,
                                                  dinv, R2, Nn, 1, Nn);
    gemm_mfma<<<dim3(512, 1), 256, 0, stream>>>(R2, Wfrags + 65536, gcn1_b, R2,
                                                n_total, strT, 1, 0);

    // 7. classes + H (MFMA + fused argmax)
    logits_mfma<<<512, 256, 0, stream>>>(R2, lin1_w, lin1_b, out_H, n_total, Nn, strT);

    // 8. hyperedge features as a mask GEMM: maskT build + split-K MFMA + reduce
    maskTb_kernel<<<Kpad / 64, 256, 0, stream>>>(out_H, maskTb, Nn, Kpad);
    he_gemm<<<KB, 256, 0, stream>>>(maskTb, R2, partials, Kpad);
    he_reduce2<<<64, 256, 0, stream>>>(partials, out_he, KB);

    // 9. dots (MFMA over 5 rho)
    bigb_copy<<<(D * NS + 255) / 256, 256, 0, stream>>>(out_he, BigB);
    bigb_mm<<<(T * D * NS + T * NS + 3) / 4, 256, 0, stream>>>(lin_w, lin_b, out_he,
                                                               BigB, beta);
    dots_mfma<<<dim3(160, 5), 256, 0, stream>>>(featb, features, useBfDots,
                                                BigB, beta, out_dots, Nn, strN);
}

// Round 10
// 987.787 us; speedup vs baseline: 1.0282x; 1.0282x over previous
//
#include <hip/hip_runtime.h>

#define D 256
#define T 4
#define NS 64

typedef unsigned int uint32;
typedef short s16x8 __attribute__((ext_vector_type(8)));
typedef float f32x4 __attribute__((ext_vector_type(4)));

// ---- bf16 helpers (manual RNE) --------------------------------------------
__device__ __forceinline__ float bflo(uint32 u) { return __uint_as_float(u << 16); }
__device__ __forceinline__ float bfhi(uint32 u) { return __uint_as_float(u & 0xffff0000u); }
__device__ __forceinline__ unsigned short f2bf(float x) {
    uint32 u = __float_as_uint(x);
    u = u + 0x7FFFu + ((u >> 16) & 1u);
    return (unsigned short)(u >> 16);
}
__device__ __forceinline__ uint32 pack2(float a, float b) {
    return (uint32)f2bf(a) | ((uint32)f2bf(b) << 16);
}
// relu on 2 packed bf16
__device__ __forceinline__ uint32 relu2(uint32 u) {
    uint32 s = u & 0x80008000u;
    uint32 m = ((s >> 15) ^ 0x00010001u) * 0xFFFFu;
    return u & m;
}

// ---------------------------------------------------------------------------
__global__ void zero_kernel(uint32* __restrict__ p, long long n)
{
    long long i = (long long)blockIdx.x * blockDim.x + threadIdx.x;
    long long st = (long long)gridDim.x * blockDim.x;
    for (; i < n; i += st) p[i] = 0u;
}

__global__ void f2bf_kernel(const float* __restrict__ in, unsigned short* __restrict__ out,
                            long long n8)
{
    long long i = (long long)blockIdx.x * blockDim.x + threadIdx.x;
    long long st = (long long)gridDim.x * blockDim.x;
    for (; i < n8; i += st) {
        float4 a = *(const float4*)(in + i * 8);
        float4 b = *(const float4*)(in + i * 8 + 4);
        uint4 o;
        o.x = pack2(a.x, a.y); o.y = pack2(a.z, a.w);
        o.z = pack2(b.x, b.y); o.w = pack2(b.z, b.w);
        *(uint4*)(out + i * 8) = o;
    }
}

// ---------------------------------------------------------------------------
// 6 weight matrices (gcn0, gcn1, lin_w[0..3]) fp32 256x256 -> B-frag-linear bf16
// ---------------------------------------------------------------------------
__global__ void wfrag_kernel(const float* __restrict__ g0, const float* __restrict__ g1,
                             const float* __restrict__ lw, unsigned short* __restrict__ out)
{
    int o = blockIdx.x * 256 + threadIdx.x;   // 0..65535
    int mat = blockIdx.y;
    const float* W = (mat == 0) ? g0 : (mat == 1) ? g1 : (lw + (size_t)(mat - 2) * 65536);
    int j = o & 7, lane = (o >> 3) & 63, ks = (o >> 9) & 7, nt = o >> 12;
    int n15 = lane & 15, quad = lane >> 4;
    int k = ks * 32 + quad * 8 + j;
    int n = nt * 16 + n15;
    out[(size_t)mat * 65536 + o] = f2bf(W[(size_t)k * 256 + n]);
}

// ---------------------------------------------------------------------------
// MFMA GEMM: C = A(bf16, Mx256) @ W(bf16 frag-linear) + bias.
// Output row: gr*rowMul + z*zRowAdd (planar batched: rowMul=1, zRowAdd=M).
// If tinvOut != nullptr, also writes per-row 1/max(||row||,1e-8) (norm of the
// bf16-rounded outputs — identical numerics to the old tinv_kernel).
// ---------------------------------------------------------------------------
__global__ __launch_bounds__(256, 2)
void gemm_mfma(const unsigned short* __restrict__ A,
               const unsigned short* __restrict__ Wfrag,
               const float* __restrict__ bias,
               unsigned short* __restrict__ Cout,
               int M, int nStripes, int rowMul, int zRowAdd,
               float* __restrict__ tinvOut)
{
    __shared__ unsigned short Asm[64 * 264];
    __shared__ float rn[64];
    int t = threadIdx.x, w = t >> 6, lane = t & 63;
    int n15 = lane & 15, quad = lane >> 4;
    int z = blockIdx.y;
    Wfrag += (size_t)z * 65536;
    bias  += (size_t)z * 256;

    s16x8 bfr[4][8];
#pragma unroll
    for (int nt = 0; nt < 4; nt++)
#pragma unroll
        for (int ks = 0; ks < 8; ks++)
            bfr[nt][ks] = *(const s16x8*)(Wfrag +
                (size_t)(((w * 4 + nt) * 8 + ks) * 64 + lane) * 8);

    float bcol[4];
#pragma unroll
    for (int nt = 0; nt < 4; nt++) bcol[nt] = bias[(w * 4 + nt) * 16 + n15];

    for (int s = blockIdx.x; s < nStripes; s += gridDim.x) {
        int m0 = s * 64;
        __syncthreads();
#pragma unroll
        for (int i = 0; i < 8; i++) {
            int idx = i * 256 + t;
            int m = idx >> 5, kc = (idx & 31) * 8;
            int gm = m0 + m;
            uint4 v = make_uint4(0u, 0u, 0u, 0u);
            if (gm < M) v = *(const uint4*)(A + (size_t)gm * 256 + kc);
            *(uint4*)(Asm + m * 264 + kc) = v;
        }
        __syncthreads();

        f32x4 acc[4][4];
#pragma unroll
        for (int rt = 0; rt < 4; rt++)
#pragma unroll
            for (int nt = 0; nt < 4; nt++)
#pragma unroll
                for (int e = 0; e < 4; e++) acc[rt][nt][e] = 0.f;

#pragma unroll
        for (int rt = 0; rt < 4; rt++) {
            int abase = (rt * 16 + n15) * 264 + quad * 8;
#pragma unroll
            for (int ks = 0; ks < 8; ks++) {
                s16x8 a = *(const s16x8*)(Asm + abase + ks * 32);
#pragma unroll
                for (int nt = 0; nt < 4; nt++)
                    acc[rt][nt] = __builtin_amdgcn_mfma_f32_16x16x32_bf16(
                        a, bfr[nt][ks], acc[rt][nt], 0, 0, 0);
            }
        }

#pragma unroll
        for (int rt = 0; rt < 4; rt++) {
            int row0 = m0 + rt * 16 + quad * 4;
#pragma unroll
            for (int nt = 0; nt < 4; nt++) {
                int colp = (w * 4 + nt) * 16 + n15;
#pragma unroll
                for (int r = 0; r < 4; r++) {
                    int gr = row0 + r;
                    if (gr < M) {
                        size_t ro = (size_t)gr * rowMul + (size_t)z * zRowAdd;
                        Cout[ro * 256 + colp] = f2bf(acc[rt][nt][r] + bcol[nt]);
                    }
                }
            }
        }

        if (tinvOut) {
            if (t < 64) rn[t] = 0.f;
            __syncthreads();
#pragma unroll
            for (int rt = 0; rt < 4; rt++)
#pragma unroll
                for (int r = 0; r < 4; r++) {
                    float p = 0.f;
#pragma unroll
                    for (int nt = 0; nt < 4; nt++) {
                        uint32 ub = ((uint32)f2bf(acc[rt][nt][r] + bcol[nt])) << 16;
                        float vv = __uint_as_float(ub);
                        p += vv * vv;
                    }
#pragma unroll
                    for (int off = 1; off < 16; off <<= 1) p += __shfl_xor(p, off);
                    if (n15 == 0)
                        atomicAdd(&rn[rt * 16 + quad * 4 + r], p);
                }
            __syncthreads();
            if (t < 64) {
                int gr2 = m0 + t;
                if (gr2 < M) {
                    size_t ro2 = (size_t)gr2 * rowMul + (size_t)z * zRowAdd;
                    tinvOut[ro2] = 1.f / fmaxf(sqrtf(rn[t]), 1e-8f);
                }
            }
        }
    }
}

// ---------------------------------------------------------------------------
// edge counting sort by dst; esorted = (src, dst) pairs in dst order
// ---------------------------------------------------------------------------
__global__ void ehist_kernel(const int* __restrict__ dst, int* __restrict__ ecnt, int E)
{
    for (int e = blockIdx.x * blockDim.x + threadIdx.x; e < E;
         e += gridDim.x * blockDim.x)
        atomicAdd(ecnt + dst[e], 1);
}

__global__ void escatter_kernel(const int* __restrict__ src, const int* __restrict__ dst,
                                const int* __restrict__ eptr, int* __restrict__ efill,
                                uint2* __restrict__ esorted, int E)
{
    for (int e = blockIdx.x * blockDim.x + threadIdx.x; e < E;
         e += gridDim.x * blockDim.x) {
        int d = dst[e];
        int pos = eptr[d] + atomicAdd(efill + d, 1);
        esorted[pos] = make_uint2((uint32)src[e], (uint32)d);
    }
}

// ---------------------------------------------------------------------------
// sim: MFMA diagonal over 16 sorted edges/wave; planar tr (replica planes
// Nn*D apart). All 8 A-fragments preloaded for burst issue.
// ---------------------------------------------------------------------------
__global__ __launch_bounds__(256)
void sim4_kernel(const uint2* __restrict__ esorted,
                 const unsigned short* __restrict__ featb,
                 const unsigned short* __restrict__ tr, const float* __restrict__ tinv,
                 int* __restrict__ bestS, int E, int Nn)
{
    int w = threadIdx.x >> 6, lane = threadIdx.x & 63;
    int n15 = lane & 15, quad = lane >> 4;
    int base = (blockIdx.x * 4 + w) * 16;
    if (base >= E) return;
    int ei = min(base + n15, E - 1);
    uint2 se = esorted[ei];
    const unsigned short* arow = featb + (size_t)se.x * D + quad * 8;
    const unsigned short* brow = tr + (size_t)se.y * D + quad * 8;
    size_t rstride = (size_t)Nn * D;

    s16x8 a[8];
#pragma unroll
    for (int ks = 0; ks < 8; ks++) a[ks] = *(const s16x8*)(arow + ks * 32);

    f32x4 a0 = {0.f, 0.f, 0.f, 0.f}, a1 = a0, a2 = a0, a3 = a0;
#pragma unroll
    for (int ks = 0; ks < 8; ks++) {
        s16x8 b0 = *(const s16x8*)(brow + ks * 32);
        a0 = __builtin_amdgcn_mfma_f32_16x16x32_bf16(a[ks], b0, a0, 0, 0, 0);
    }
#pragma unroll
    for (int ks = 0; ks < 8; ks++) {
        s16x8 b1 = *(const s16x8*)(brow + rstride + ks * 32);
        a1 = __builtin_amdgcn_mfma_f32_16x16x32_bf16(a[ks], b1, a1, 0, 0, 0);
    }
#pragma unroll
    for (int ks = 0; ks < 8; ks++) {
        s16x8 b2 = *(const s16x8*)(brow + 2 * rstride + ks * 32);
        a2 = __builtin_amdgcn_mfma_f32_16x16x32_bf16(a[ks], b2, a2, 0, 0, 0);
    }
#pragma unroll
    for (int ks = 0; ks < 8; ks++) {
        s16x8 b3 = *(const s16x8*)(brow + 3 * rstride + ks * 32);
        a3 = __builtin_amdgcn_mfma_f32_16x16x32_bf16(a[ks], b3, a3, 0, 0, 0);
    }

    if (quad == (n15 >> 2) && base + n15 < E) {
        int r = n15 & 3;
        int d = (int)se.y;
        float v0 = a0[r] * tinv[d];
        float v1 = a1[r] * tinv[Nn + d];
        float v2 = a2[r] * tinv[2 * Nn + d];
        float v3 = a3[r] * tinv[3 * Nn + d];
        float bv = v0; int bi = 0;
        if (v1 > bv) { bv = v1; bi = 1; }   // strict >: first-index ties
        if (v2 > bv) { bv = v2; bi = 2; }
        if (v3 > bv) { bv = v3; bi = 3; }
        bestS[base + n15] = bi;
    }
}

// ---------------------------------------------------------------------------
// unified edge list over SORTED edges (degree histogram only)
// ---------------------------------------------------------------------------
__device__ __forceinline__ void decode_edge(int e, const uint2* __restrict__ esorted,
                                            const int* __restrict__ bestS,
                                            int E, int Nn, int& s, int& d, bool& keep)
{
    if (e < E) {
        uint2 se = esorted[e];
        s = (int)se.x; d = (int)se.y; keep = (s != d);
    } else if (e < 2 * E) {
        int k = e - E;
        uint2 se = esorted[k];
        s = (int)se.x; d = (int)se.y + bestS[k] * Nn; keep = (s != d);
    } else if (e < 2 * E + T * Nn) {
        int k = e - 2 * E; int i = k / Nn; int n = k - i * Nn;
        s = n; d = n + i * Nn; keep = (i != 0);
    } else {
        int v = e - (2 * E + T * Nn); s = v; d = v; keep = true;
    }
}

__global__ void hist_kernel(const uint2* __restrict__ esorted, const int* __restrict__ bestS,
                            int* __restrict__ cnt, int E, int Nn)
{
    int total = 2 * E + (2 * T + 1) * Nn;
    for (int e = blockIdx.x * blockDim.x + threadIdx.x; e < total;
         e += gridDim.x * blockDim.x) {
        int s, d; bool keep;
        decode_edge(e, esorted, bestS, E, Nn, s, d, keep);
        if (keep) atomicAdd(cnt + d, 1);
    }
}

// ---------------------------------------------------------------------------
// merged: dinv for all rows + per-edge packed meta (src | best<<27, dinv[src])
// cnt >= 1 for every row (self loop) so rsqrt is safe.
// ---------------------------------------------------------------------------
__global__ void emeta_dinv_kernel(const uint2* __restrict__ esorted,
                                  const int* __restrict__ bestS,
                                  const int* __restrict__ cnt,
                                  float* __restrict__ dinv, uint2* __restrict__ emeta,
                                  int E, int n_total, int work)
{
    for (int i = blockIdx.x * blockDim.x + threadIdx.x; i < work;
         i += gridDim.x * blockDim.x) {
        if (i < n_total) {
            int c = cnt[i];
            dinv[i] = (c > 0) ? rsqrtf((float)c) : 0.f;
        }
        if (i < E) {
            uint2 se = esorted[i];
            uint32 packed = se.x | ((uint32)bestS[i] << 27);
            float dv = rsqrtf((float)cnt[se.x]);
            emeta[i] = make_uint2(packed, __float_as_uint(dv));
        }
    }
}

__global__ void scan_sums(const int* __restrict__ cnt, int* __restrict__ aux, int n)
{
    __shared__ int sd[256];
    int idx = blockIdx.x * 256 + threadIdx.x;
    sd[threadIdx.x] = (idx < n) ? cnt[idx] : 0;
    __syncthreads();
    for (int off = 128; off; off >>= 1) {
        if (threadIdx.x < off) sd[threadIdx.x] += sd[threadIdx.x + off];
        __syncthreads();
    }
    if (threadIdx.x == 0) aux[blockIdx.x] = sd[0];
}

__global__ void scan_aux(const int* __restrict__ aux, int* __restrict__ auxex, int nb)
{
    __shared__ int sd[1024];
    int t = threadIdx.x;
    int v = (t < nb) ? aux[t] : 0;
    sd[t] = v;
    __syncthreads();
    for (int off = 1; off < 1024; off <<= 1) {
        int x = (t >= off) ? sd[t - off] : 0;
        __syncthreads();
        sd[t] += x;
        __syncthreads();
    }
    if (t < nb) auxex[t] = sd[t] - v;
}

__global__ void scan_write(const int* __restrict__ cnt, const int* __restrict__ auxex,
                           int* __restrict__ rowptr, int n)
{
    __shared__ int sd[256];
    int t = threadIdx.x;
    int idx = blockIdx.x * 256 + t;
    int v = (idx < n) ? cnt[idx] : 0;
    sd[t] = v;
    __syncthreads();
    for (int off = 1; off < 256; off <<= 1) {
        int x = (t >= off) ? sd[t - off] : 0;
        __syncthreads();
        sd[t] += x;
        __syncthreads();
    }
    if (idx < n) {
        int rp = auxex[blockIdx.x] + sd[t] - v;
        rowptr[idx] = rp;
        if (idx == n - 1) rowptr[n] = rp + v;
    }
}

// ---------------------------------------------------------------------------
// agg5: one wave per BASE node v, produces all 5 output rows {v, v+iN}.
// xb replica row for node v, replica i: v*xrm + i*xra
// ---------------------------------------------------------------------------
__global__ __launch_bounds__(256)
void agg5_kernel(const int* __restrict__ eptr, const uint2* __restrict__ emeta,
                 const unsigned short* __restrict__ xa,
                 const unsigned short* __restrict__ xb,
                 const float* __restrict__ dinv,
                 unsigned short* __restrict__ outb, int Nn, int xrm, int xra)
{
    int wave = threadIdx.x >> 6, lane = threadIdx.x & 63;
    int v = blockIdx.x * 4 + wave;
    if (v >= Nn) return;

    float dv  = dinv[v];
    float dr1 = dinv[v + Nn];
    float dr2 = dinv[v + 2 * Nn];
    float dr3 = dinv[v + 3 * Nn];
    float dr4 = dinv[v + 4 * Nn];

    uint2 qv = *(const uint2*)(xa + (size_t)v * D + lane * 4);
    qv.x = relu2(qv.x); qv.y = relu2(qv.y);
    float y0 = bflo(qv.x), y1 = bfhi(qv.x), y2 = bflo(qv.y), y3 = bfhi(qv.y);

    float wsb = dv * dv;
    float b0 = wsb * y0, b1 = wsb * y1, b2 = wsb * y2, b3 = wsb * y3;

    float wi1 = dv * dr1, wi2 = dv * dr2, wi3 = dv * dr3;
    float r10 = wi1 * y0, r11 = wi1 * y1, r12 = wi1 * y2, r13 = wi1 * y3;
    float r20 = wi2 * y0, r21 = wi2 * y1, r22 = wi2 * y2, r23 = wi2 * y3;
    float r30 = wi3 * y0, r31 = wi3 * y1, r32 = wi3 * y2, r33 = wi3 * y3;
    float r40 = 0.f, r41 = 0.f, r42 = 0.f, r43 = 0.f;

    {
        uint2 q = *(const uint2*)(xb + ((size_t)v * xrm + 0 * (size_t)xra) * D + lane * 4);
        q.x = relu2(q.x); q.y = relu2(q.y);
        float ws = dr1 * dr1;
        r10 = fmaf(ws, bflo(q.x), r10); r11 = fmaf(ws, bfhi(q.x), r11);
        r12 = fmaf(ws, bflo(q.y), r12); r13 = fmaf(ws, bfhi(q.y), r13);
    }
    {
        uint2 q = *(const uint2*)(xb + ((size_t)v * xrm + 1 * (size_t)xra) * D + lane * 4);
        q.x = relu2(q.x); q.y = relu2(q.y);
        float ws = dr2 * dr2;
        r20 = fmaf(ws, bflo(q.x), r20); r21 = fmaf(ws, bfhi(q.x), r21);
        r22 = fmaf(ws, bflo(q.y), r22); r23 = fmaf(ws, bfhi(q.y), r23);
    }
    {
        uint2 q = *(const uint2*)(xb + ((size_t)v * xrm + 2 * (size_t)xra) * D + lane * 4);
        q.x = relu2(q.x); q.y = relu2(q.y);
        float ws = dr3 * dr3;
        r30 = fmaf(ws, bflo(q.x), r30); r31 = fmaf(ws, bfhi(q.x), r31);
        r32 = fmaf(ws, bflo(q.y), r32); r33 = fmaf(ws, bfhi(q.y), r33);
    }
    {
        uint2 q = *(const uint2*)(xb + ((size_t)v * xrm + 3 * (size_t)xra) * D + lane * 4);
        q.x = relu2(q.x); q.y = relu2(q.y);
        float ws = dr4 * dr4;
        r40 = fmaf(ws, bflo(q.x), r40); r41 = fmaf(ws, bfhi(q.x), r41);
        r42 = fmaf(ws, bflo(q.y), r42); r43 = fmaf(ws, bfhi(q.y), r43);
    }

    int j = eptr[v], jend = eptr[v + 1];

#define EDGE_META(mm, ssu, wws)                                                    \
    uint32 ssu = (uint32)__builtin_amdgcn_readfirstlane((int)mm.x);                \
    float wws = __uint_as_float((uint32)__builtin_amdgcn_readfirstlane((int)mm.y));

#define EDGE_BODY(qq, ss, bb, ww)                                                  \
    {                                                                              \
        float x0 = bflo(qq.x), x1 = bfhi(qq.x), x2 = bflo(qq.y), x3 = bfhi(qq.y);  \
        float wb = (ss != v) ? (ww) * dv : 0.f;                                    \
        if (bb == 0) wb += wb;                                                     \
        b0 = fmaf(wb, x0, b0); b1 = fmaf(wb, x1, b1);                              \
        b2 = fmaf(wb, x2, b2); b3 = fmaf(wb, x3, b3);                              \
        if (bb == 1) {                                                             \
            float wr = (ww) * dr1;                                                 \
            r10 = fmaf(wr, x0, r10); r11 = fmaf(wr, x1, r11);                      \
            r12 = fmaf(wr, x2, r12); r13 = fmaf(wr, x3, r13);                      \
        } else if (bb == 2) {                                                      \
            float wr = (ww) * dr2;                                                 \
            r20 = fmaf(wr, x0, r20); r21 = fmaf(wr, x1, r21);                      \
            r22 = fmaf(wr, x2, r22); r23 = fmaf(wr, x3, r23);                      \
        } else if (bb == 3) {                                                      \
            float wr = (ww) * dr3;                                                 \
            r30 = fmaf(wr, x0, r30); r31 = fmaf(wr, x1, r31);                      \
            r32 = fmaf(wr, x2, r32); r33 = fmaf(wr, x3, r33);                      \
        }                                                                          \
    }

    for (; j + 4 <= jend; j += 4) {
        uint2 m0 = emeta[j];
        uint2 m1 = emeta[j + 1];
        uint2 m2 = emeta[j + 2];
        uint2 m3 = emeta[j + 3];
        EDGE_META(m0, su0, ws0); EDGE_META(m1, su1, ws1);
        EDGE_META(m2, su2, ws2); EDGE_META(m3, su3, ws3);
        int s0 = (int)(su0 & 0x07FFFFFFu), bx0 = (int)(su0 >> 27);
        int s1 = (int)(su1 & 0x07FFFFFFu), bx1 = (int)(su1 >> 27);
        int s2 = (int)(su2 & 0x07FFFFFFu), bx2 = (int)(su2 >> 27);
        int s3 = (int)(su3 & 0x07FFFFFFu), bx3 = (int)(su3 >> 27);
        uint2 q0 = *(const uint2*)(xa + (size_t)s0 * D + lane * 4);
        uint2 q1 = *(const uint2*)(xa + (size_t)s1 * D + lane * 4);
        uint2 q2 = *(const uint2*)(xa + (size_t)s2 * D + lane * 4);
        uint2 q3 = *(const uint2*)(xa + (size_t)s3 * D + lane * 4);
        q0.x = relu2(q0.x); q0.y = relu2(q0.y);
        q1.x = relu2(q1.x); q1.y = relu2(q1.y);
        q2.x = relu2(q2.x); q2.y = relu2(q2.y);
        q3.x = relu2(q3.x); q3.y = relu2(q3.y);
        EDGE_BODY(q0, s0, bx0, ws0);
        EDGE_BODY(q1, s1, bx1, ws1);
        EDGE_BODY(q2, s2, bx2, ws2);
        EDGE_BODY(q3, s3, bx3, ws3);
    }
    for (; j + 2 <= jend; j += 2) {
        uint2 m0 = emeta[j];
        uint2 m1 = emeta[j + 1];
        EDGE_META(m0, su0, ws0); EDGE_META(m1, su1, ws1);
        int s0 = (int)(su0 & 0x07FFFFFFu), bx0 = (int)(su0 >> 27);
        int s1 = (int)(su1 & 0x07FFFFFFu), bx1 = (int)(su1 >> 27);
        uint2 q0 = *(const uint2*)(xa + (size_t)s0 * D + lane * 4);
        uint2 q1 = *(const uint2*)(xa + (size_t)s1 * D + lane * 4);
        q0.x = relu2(q0.x); q0.y = relu2(q0.y);
        q1.x = relu2(q1.x); q1.y = relu2(q1.y);
        EDGE_BODY(q0, s0, bx0, ws0);
        EDGE_BODY(q1, s1, bx1, ws1);
    }
    if (j < jend) {
        uint2 m0 = emeta[j];
        EDGE_META(m0, su0, ws0);
        int s0 = (int)(su0 & 0x07FFFFFFu), bx0 = (int)(su0 >> 27);
        uint2 q0 = *(const uint2*)(xa + (size_t)s0 * D + lane * 4);
        q0.x = relu2(q0.x); q0.y = relu2(q0.y);
        EDGE_BODY(q0, s0, bx0, ws0);
    }
#undef EDGE_BODY
#undef EDGE_META

    uint2 o;
    o.x = pack2(b0, b1); o.y = pack2(b2, b3);
    *(uint2*)(outb + (size_t)v * D + lane * 4) = o;
    o.x = pack2(r10, r11); o.y = pack2(r12, r13);
    *(uint2*)(outb + ((size_t)v + Nn) * D + lane * 4) = o;
    o.x = pack2(r20, r21); o.y = pack2(r22, r23);
    *(uint2*)(outb + ((size_t)v + 2 * (size_t)Nn) * D + lane * 4) = o;
    o.x = pack2(r30, r31); o.y = pack2(r32, r33);
    *(uint2*)(outb + ((size_t)v + 3 * (size_t)Nn) * D + lane * 4) = o;
    o.x = pack2(r40, r41); o.y = pack2(r42, r43);
    *(uint2*)(outb + ((size_t)v + 4 * (size_t)Nn) * D + lane * 4) = o;
}

// ---------------------------------------------------------------------------
// MFMA logits + fused argmax + H
// ---------------------------------------------------------------------------
__global__ __launch_bounds__(256, 2)
void logits_mfma(const unsigned short* __restrict__ af2, const float* __restrict__ Wl,
                 const float* __restrict__ bl, float* __restrict__ H,
                 int M, int Nn, int nStripes)
{
    __shared__ unsigned short Asm[64 * 264];
    int t = threadIdx.x, w = t >> 6, lane = t & 63;
    int n15 = lane & 15, quad = lane >> 4;

    s16x8 bfr[4][8];
#pragma unroll
    for (int nt = 0; nt < 4; nt++)
#pragma unroll
        for (int ks = 0; ks < 8; ks++) {
            s16x8 f;
#pragma unroll
            for (int j = 0; j < 8; j++) {
                int k = ks * 32 + quad * 8 + j;
                f[j] = (short)f2bf(Wl[(size_t)k * NS + nt * 16 + n15]);
            }
            bfr[nt][ks] = f;
        }
    float bcol[4];
#pragma unroll
    for (int nt = 0; nt < 4; nt++) bcol[nt] = bl[nt * 16 + n15];

    for (int s = blockIdx.x; s < nStripes; s += gridDim.x) {
        int m0 = s * 64;
        __syncthreads();
#pragma unroll
        for (int i = 0; i < 8; i++) {
            int idx = i * 256 + t;
            int m = idx >> 5, kc = (idx & 31) * 8;
            int gm = m0 + m;
            uint4 v = make_uint4(0u, 0u, 0u, 0u);
            if (gm < M) {
                v = *(const uint4*)(af2 + (size_t)gm * 256 + kc);
                v.x = relu2(v.x); v.y = relu2(v.y);
                v.z = relu2(v.z); v.w = relu2(v.w);
            }
            *(uint4*)(Asm + m * 264 + kc) = v;
        }
        __syncthreads();

        f32x4 acc[4];
#pragma unroll
        for (int nt = 0; nt < 4; nt++)
#pragma unroll
            for (int e = 0; e < 4; e++) acc[nt][e] = 0.f;

        int abase = (w * 16 + n15) * 264 + quad * 8;
#pragma unroll
        for (int ks = 0; ks < 8; ks++) {
            s16x8 a = *(const s16x8*)(Asm + abase + ks * 32);
#pragma unroll
            for (int nt = 0; nt < 4; nt++)
                acc[nt] = __builtin_amdgcn_mfma_f32_16x16x32_bf16(
                    a, bfr[nt][ks], acc[nt], 0, 0, 0);
        }

#pragma unroll
        for (int e = 0; e < 4; e++) {
            float bv = acc[0][e] + bcol[0]; int bi = n15;
#pragma unroll
            for (int nt = 1; nt < 4; nt++) {
                float v = acc[nt][e] + bcol[nt];
                int c = nt * 16 + n15;
                if (v > bv) { bv = v; bi = c; }
            }
#pragma unroll
            for (int off = 1; off < 16; off <<= 1) {
                float ov = __shfl_xor(bv, off);
                int   oi = __shfl_xor(bi, off);
                if (ov > bv || (ov == bv && oi < bi)) { bv = ov; bi = oi; }
            }
            if (n15 == 0) {
                int gr = m0 + w * 16 + quad * 4 + e;
                if (gr < M) atomicAdd(H + (size_t)(gr % Nn) * NS + bi, 1.0f);
            }
        }
    }
}

// ---------------------------------------------------------------------------
// maskTb: H (Nn x NS fp32) -> bf16 maskT [NS][Kpad] (1.0 where H>0, else 0),
// zero-padded in [Nn, Kpad). LDS-tiled transpose, coalesced both sides.
// ---------------------------------------------------------------------------
__global__ __launch_bounds__(256)
void maskTb_kernel(const float* __restrict__ H, unsigned short* __restrict__ maskTb,
                   int Nn, int Kpad)
{
    __shared__ unsigned short tile[64 * 72];   // [c][n], pad 72
    int t = threadIdx.x;
    int n0 = blockIdx.x * 64;
    int c = t & 63, rr = t >> 6;
#pragma unroll
    for (int i = 0; i < 16; i++) {
        int n = rr + i * 4;
        float hv = (n0 + n < Nn) ? H[(size_t)(n0 + n) * NS + c] : 0.f;
        tile[c * 72 + n] = (hv > 0.f) ? (unsigned short)0x3F80 : (unsigned short)0;
    }
    __syncthreads();
#pragma unroll
    for (int i = 0; i < 2; i++) {
        int idx = i * 256 + t;              // 0..511: 64 rows x 8 chunks
        int cc = idx >> 3, ch = idx & 7;
        uint4 v = *(const uint4*)(tile + cc * 72 + ch * 8);
        *(uint4*)(maskTb + (size_t)cc * Kpad + n0 + ch * 8) = v;
    }
}

// ---------------------------------------------------------------------------
// he_gemm: he = maskTb (64 x Kpad bf16) @ af2 (Kpad x 256 bf16), split-K.
// ---------------------------------------------------------------------------
__global__ __launch_bounds__(256, 2)
void he_gemm(const unsigned short* __restrict__ maskTb,
             const unsigned short* __restrict__ af2,
             float* __restrict__ partials, int Kpad)
{
    __shared__ unsigned short Bsm[32 * 264];
    int t = threadIdx.x, w = t >> 6, lane = t & 63;
    int n15 = lane & 15, quad = lane >> 4;
    int k0 = blockIdx.x * 256;

    f32x4 acc[4][4];
#pragma unroll
    for (int mt = 0; mt < 4; mt++)
#pragma unroll
        for (int nt = 0; nt < 4; nt++)
#pragma unroll
            for (int e = 0; e < 4; e++) acc[mt][nt][e] = 0.f;

    for (int s = 0; s < 8; s++) {
        int k = k0 + s * 32;
        __syncthreads();
#pragma unroll
        for (int i = 0; i < 4; i++) {
            int idx = i * 256 + t;              // 0..1023: 32 rows x 32 chunks
            int row = idx >> 5, col8 = (idx & 31) * 8;
            uint4 v = *(const uint4*)(af2 + (size_t)(k + row) * 256 + col8);
            *(uint4*)(Bsm + row * 264 + col8) = v;
        }
        __syncthreads();

        s16x8 a[4];
#pragma unroll
        for (int mt = 0; mt < 4; mt++)
            a[mt] = *(const s16x8*)(maskTb + (size_t)(mt * 16 + n15) * Kpad
                                    + k + quad * 8);
#pragma unroll
        for (int nt = 0; nt < 4; nt++) {
            int ncol = w * 64 + nt * 16 + n15;
            s16x8 b;
#pragma unroll
            for (int j = 0; j < 8; j++)
                b[j] = (short)Bsm[(quad * 8 + j) * 264 + ncol];
#pragma unroll
            for (int mt = 0; mt < 4; mt++)
                acc[mt][nt] = __builtin_amdgcn_mfma_f32_16x16x32_bf16(
                    a[mt], b, acc[mt][nt], 0, 0, 0);
        }
    }

    float* pdst = partials + (size_t)blockIdx.x * (64 * 256);
#pragma unroll
    for (int mt = 0; mt < 4; mt++)
#pragma unroll
        for (int nt = 0; nt < 4; nt++)
#pragma unroll
            for (int r = 0; r < 4; r++) {
                int m = mt * 16 + quad * 4 + r;
                int n = w * 64 + nt * 16 + n15;
                pdst[(size_t)m * 256 + n] = acc[mt][nt][r];
            }
}

// ---------------------------------------------------------------------------
// he_reduce2: out_he[c][f] = sum_b partials[b][c][f]  (plain store)
// ---------------------------------------------------------------------------
__global__ __launch_bounds__(256)
void he_reduce2(const float* __restrict__ partials, float* __restrict__ he, int KB)
{
    int idx = blockIdx.x * 256 + threadIdx.x;   // 0..16383
    float s = 0.f;
    for (int b = 0; b < KB; b++)
        s += partials[(size_t)b * 16384 + idx];
    he[idx] = s;
}

// ---------------------------------------------------------------------------
__global__ void bigb_copy(const float* __restrict__ he, float* __restrict__ BigB)
{
    int idx = blockIdx.x * 256 + threadIdx.x;
    if (idx < D * NS) {
        int d = idx >> 6, c = idx & 63;
        BigB[idx] = he[(size_t)c * D + d];
    }
}

__global__ __launch_bounds__(256)
void bigb_mm(const float* __restrict__ lin_w, const float* __restrict__ lin_b,
             const float* __restrict__ he, float* __restrict__ BigB,
             float* __restrict__ beta)
{
    int gw = (int)((blockIdx.x * 256 + threadIdx.x) >> 6);
    int lane = threadIdx.x & 63;
    const int totalA = T * D * NS;
    if (gw >= totalA + T * NS) return;
    const float* xrow; const float* hrow; float* outp;
    if (gw < totalA) {
        int t = gw / (D * NS); int rem = gw - t * D * NS;
        int d = rem / NS; int c = rem - d * NS;
        xrow = lin_w + ((size_t)t * D + d) * D;
        hrow = he + (size_t)c * D;
        outp = BigB + ((size_t)(t + 1) * D + d) * NS + c;
    } else {
        int i = gw - totalA; int t = i / NS; int c = i - t * NS;
        xrow = lin_b + (size_t)t * D;
        hrow = he + (size_t)c * D;
        outp = beta + (size_t)(t + 1) * NS + c;
    }
    float4 x = *(const float4*)(xrow + lane * 4);
    float4 h = *(const float4*)(hrow + lane * 4);
    float s = x.x * h.x + x.y * h.y + x.z * h.z + x.w * h.w;
#pragma unroll
    for (int off = 32; off; off >>= 1) s += __shfl_xor(s, off);
    if (lane == 0) *outp = s;
}

// ---------------------------------------------------------------------------
// MFMA dots: A-rows from featb (bf16, useBf=1, must NOT alias dots) or
// staged fp32 feat (useBf=0). grid (nBlk, 5)
// ---------------------------------------------------------------------------
__global__ __launch_bounds__(256, 2)
void dots_mfma(const unsigned short* __restrict__ featb,
               const float* __restrict__ feat32, int useBf,
               const float* __restrict__ BigB,
               const float* __restrict__ beta, float* __restrict__ dots,
               int Nn, int nStripes)
{
    __shared__ unsigned short Asm[64 * 264];
    int t = threadIdx.x, w = t >> 6, lane = t & 63;
    int n15 = lane & 15, quad = lane >> 4;
    int rho = blockIdx.y;
    const float* Bp = BigB + (size_t)rho * D * NS;

    s16x8 bfr[4][8];
#pragma unroll
    for (int nt = 0; nt < 4; nt++)
#pragma unroll
        for (int ks = 0; ks < 8; ks++) {
            s16x8 f;
#pragma unroll
            for (int j = 0; j < 8; j++) {
                int k = ks * 32 + quad * 8 + j;
                f[j] = (short)f2bf(Bp[(size_t)k * NS + nt * 16 + n15]);
            }
            bfr[nt][ks] = f;
        }
    float bcol[4];
#pragma unroll
    for (int nt = 0; nt < 4; nt++) bcol[nt] = beta[rho * NS + nt * 16 + n15];

    for (int s = blockIdx.x; s < nStripes; s += gridDim.x) {
        int m0 = s * 64;
        __syncthreads();
#pragma unroll
        for (int i = 0; i < 8; i++) {
            int idx = i * 256 + t;
            int m = idx >> 5, kc = (idx & 31) * 8;
            int gm = m0 + m;
            uint4 o = make_uint4(0u, 0u, 0u, 0u);
            if (gm < Nn) {
                if (useBf) {
                    o = *(const uint4*)(featb + (size_t)gm * 256 + kc);
                } else {
                    float4 a = *(const float4*)(feat32 + (size_t)gm * 256 + kc);
                    float4 b = *(const float4*)(feat32 + (size_t)gm * 256 + kc + 4);
                    o.x = pack2(a.x, a.y); o.y = pack2(a.z, a.w);
                    o.z = pack2(b.x, b.y); o.w = pack2(b.z, b.w);
                }
            }
            *(uint4*)(Asm + m * 264 + kc) = o;
        }
        __syncthreads();

        f32x4 acc[4];
#pragma unroll
        for (int nt = 0; nt < 4; nt++)
#pragma unroll
            for (int e = 0; e < 4; e++) acc[nt][e] = 0.f;

        int abase = (w * 16 + n15) * 264 + quad * 8;
#pragma unroll
        for (int ks = 0; ks < 8; ks++) {
            s16x8 a = *(const s16x8*)(Asm + abase + ks * 32);
#pragma unroll
            for (int nt = 0; nt < 4; nt++)
                acc[nt] = __builtin_amdgcn_mfma_f32_16x16x32_bf16(
                    a, bfr[nt][ks], acc[nt], 0, 0, 0);
        }

#pragma unroll
        for (int e = 0; e < 4; e++) {
            int gr = m0 + w * 16 + quad * 4 + e;
            if (gr >= Nn) continue;
#pragma unroll
            for (int nt = 0; nt < 4; nt++) {
                int c = nt * 16 + n15;
                dots[((size_t)rho * Nn + gr) * NS + c] = (acc[nt][e] + bcol[nt]) * 0.0625f;
            }
        }
    }
}

// ---------------------------------------------------------------------------
extern "C" void kernel_launch(void* const* d_in, const int* in_sizes, int n_in,
                              void* d_out, int out_size, void* d_ws, size_t ws_size,
                              hipStream_t stream)
{
    const int*   edge_index = (const int*)d_in[0];
    const float* features   = (const float*)d_in[1];
    const float* lin_w      = (const float*)d_in[2];
    const float* lin_b      = (const float*)d_in[3];
    const float* gcn0_w     = (const float*)d_in[4];
    const float* gcn0_b     = (const float*)d_in[5];
    const float* gcn1_w     = (const float*)d_in[6];
    const float* gcn1_b     = (const float*)d_in[7];
    const float* lin1_w     = (const float*)d_in[8];
    const float* lin1_b     = (const float*)d_in[9];

    int E  = in_sizes[0] / 2;
    int Nn = in_sizes[1] / D;
    int n_total = (T + 1) * Nn;
    int Mrep = T * Nn;

    const int* src = edge_index;
    const int* dst = edge_index + E;

    float* out_H    = (float*)d_out;
    float* out_he   = out_H + (size_t)Nn * NS;
    float* out_dots = out_he + (size_t)NS * D;

    // he GEMM split-K geometry
    int KB   = (Nn + 255) / 256;      // blocks, 256 K per block
    int Kpad = KB * 256;

    // ---- ws carve: two big bf16 regions + BigB (+ featb if it fits)
    char* ws0 = (char*)d_ws;
    char* wsp = ws0;
    auto carve = [&](size_t bytes) {
        char* p = wsp; wsp += (bytes + 255) & ~(size_t)255; return p;
    };
    unsigned short* R1   = (unsigned short*)carve((size_t)n_total * D * 2);
    unsigned short* R2   = (unsigned short*)carve((size_t)n_total * D * 2);
    float*          BigB = (float*)carve((size_t)(T + 1) * D * NS * 4);
    float*          beta = (float*)carve((size_t)(T + 1) * NS * 4);
    unsigned short* transformed = R2;   // planar prefix of R2 (T*Nn rows)

    // featb: prefer ws (safe to read during dots_mfma); fall back to the
    // out_dots scratch region + fp32 staging in dots_mfma.
    size_t featb_bytes = (size_t)Nn * D * 2;
    unsigned short* featb = nullptr;
    int useBfDots = 0;
    if ((size_t)(wsp - ws0) + featb_bytes + 256 <= ws_size) {
        featb = (unsigned short*)carve(featb_bytes);
        useBfDots = 1;
    }

    // ---- scratch in the out_dots region (dead before dots_mfma)
    char* sc = (char*)out_dots;
    auto carve2 = [&](size_t bytes) {
        char* p = sc; sc += (bytes + 255) & ~(size_t)255; return p;
    };
    float* tinv    = (float*)carve2((size_t)Mrep * 4);
    int*   best    = (int*)carve2((size_t)E * 4);       // SORTED order
    // cnt / ecnt / efill contiguous -> single zero launch
    int*   cnt     = (int*)carve2((size_t)(n_total + 2 * Nn) * 4);
    int*   ecnt    = cnt + n_total;
    int*   efill   = ecnt + Nn;
    float* dinv    = (float*)carve2((size_t)n_total * 4);
    int*   aux     = (int*)carve2(1024 * 4);
    int*   auxex   = (int*)carve2(1024 * 4);
    if (!featb) featb = (unsigned short*)carve2(featb_bytes);
    unsigned short* Wfrags = (unsigned short*)carve2((size_t)6 * 65536 * 2);
    int*   eptr    = (int*)carve2((size_t)(Nn + 1) * 4);
    uint2* esorted = (uint2*)carve2((size_t)E * 8);     // (src, dst) in dst order
    uint2* emeta   = (uint2*)carve2((size_t)E * 8);     // (src|best<<27, dinv[src])
    unsigned short* maskTb = (unsigned short*)carve2((size_t)NS * Kpad * 2);

    // he_gemm partials live in R1 (dead after layer-1 agg): KB*64KB ~ 12.8MB
    float* partials = (float*)R1;

    // ---- zero accumulators (merged: cnt+ecnt+efill in one shot)
    zero_kernel<<<512, 256, 0, stream>>>((uint32*)cnt, (long long)(n_total + 2 * Nn));
    zero_kernel<<<512, 256, 0, stream>>>((uint32*)out_H, (long long)Nn * NS + NS * D);
    zero_kernel<<<1, 256, 0, stream>>>((uint32*)beta, (T + 1) * NS);

    // 0. conversions
    wfrag_kernel<<<dim3(256, 6), 256, 0, stream>>>(gcn0_w, gcn1_w, lin_w, Wfrags);
    f2bf_kernel<<<2048, 256, 0, stream>>>(features, featb, (long long)Nn * D / 8);

    // 1. transformed[z*Nn + n] = featb[n] @ lin_w[z] + lin_b[z], fused row norms
    int strN = (Nn + 63) / 64;
    gemm_mfma<<<dim3(512, T), 256, 0, stream>>>(featb, Wfrags + 2 * 65536, lin_b,
                                                transformed, Nn, strN, 1, Nn, tinv);

    // 2. edge sort by dst + MFMA-diagonal sim
    ehist_kernel<<<2048, 256, 0, stream>>>(dst, ecnt, E);
    int enb = (Nn + 255) / 256;
    scan_sums<<<enb, 256, 0, stream>>>(ecnt, aux, Nn);
    scan_aux<<<1, 1024, 0, stream>>>(aux, auxex, enb);
    scan_write<<<enb, 256, 0, stream>>>(ecnt, auxex, eptr, Nn);
    escatter_kernel<<<2048, 256, 0, stream>>>(src, dst, eptr, efill, esorted, E);
    int nGroups = (E + 15) / 16;
    sim4_kernel<<<(nGroups + 3) / 4, 256, 0, stream>>>(esorted, featb, transformed,
                                                       tinv, best, E, Nn);

    // 3. degrees -> dinv + packed per-edge meta (merged)
    hist_kernel<<<2048, 256, 0, stream>>>(esorted, best, cnt, E, Nn);
    int work = (E > n_total) ? E : n_total;
    emeta_dinv_kernel<<<2048, 256, 0, stream>>>(esorted, best, cnt, dinv, emeta,
                                                E, n_total, work);

    // 4. layer 0 (xb = transformed, planar replica planes)
    int strT = (n_total + 63) / 64;
    agg5_kernel<<<(Nn + 3) / 4, 256, 0, stream>>>(eptr, emeta, featb, transformed,
                                                  dinv, R1, Nn, 1, Nn);
    gemm_mfma<<<dim3(512, 1), 256, 0, stream>>>(R1, Wfrags, gcn0_b, R1, n_total,
                                                strT, 1, 0, nullptr);

    // 5. layer 1 (xb = R1 planar replicas)
    agg5_kernel<<<(Nn + 3) / 4, 256, 0, stream>>>(eptr, emeta, R1, R1 + (size_t)Nn * D,
                                                  dinv, R2, Nn, 1, Nn);
    gemm_mfma<<<dim3(512, 1), 256, 0, stream>>>(R2, Wfrags + 65536, gcn1_b, R2,
                                                n_total, strT, 1, 0, nullptr);

    // 6. classes + H (MFMA + fused argmax)
    logits_mfma<<<512, 256, 0, stream>>>(R2, lin1_w, lin1_b, out_H, n_total, Nn, strT);

    // 7. hyperedge features as a mask GEMM: maskT build + split-K MFMA + reduce
    maskTb_kernel<<<Kpad / 64, 256, 0, stream>>>(out_H, maskTb, Nn, Kpad);
    he_gemm<<<KB, 256, 0, stream>>>(maskTb, R2, partials, Kpad);
    he_reduce2<<<64, 256, 0, stream>>>(partials, out_he, KB);

    // 8. dots (MFMA over 5 rho)
    bigb_copy<<<(D * NS + 255) / 256, 256, 0, stream>>>(out_he, BigB);
    bigb_mm<<<(T * D * NS + T * NS + 3) / 4, 256, 0, stream>>>(lin_w, lin_b, out_he,
                                                               BigB, beta);
    dots_mfma<<<dim3(160, 5), 256, 0, stream>>>(featb, features, useBfDots,
                                                BigB, beta, out_dots, Nn, strN);
}

// Round 11
// 945.065 us; speedup vs baseline: 1.0747x; 1.0452x over previous
//
#include <hip/hip_runtime.h>

#define D 256
#define T 4
#define NS 64

typedef unsigned int uint32;
typedef short s16x8 __attribute__((ext_vector_type(8)));
typedef float f32x4 __attribute__((ext_vector_type(4)));

// ---- bf16 helpers (manual RNE) --------------------------------------------
__device__ __forceinline__ float bflo(uint32 u) { return __uint_as_float(u << 16); }
__device__ __forceinline__ float bfhi(uint32 u) { return __uint_as_float(u & 0xffff0000u); }
__device__ __forceinline__ unsigned short f2bf(float x) {
    uint32 u = __float_as_uint(x);
    u = u + 0x7FFFu + ((u >> 16) & 1u);
    return (unsigned short)(u >> 16);
}
__device__ __forceinline__ uint32 pack2(float a, float b) {
    return (uint32)f2bf(a) | ((uint32)f2bf(b) << 16);
}
// relu on 2 packed bf16
__device__ __forceinline__ uint32 relu2(uint32 u) {
    uint32 s = u & 0x80008000u;
    uint32 m = ((s >> 15) ^ 0x00010001u) * 0xFFFFu;
    return u & m;
}

// ---------------------------------------------------------------------------
__global__ void zero_kernel(uint32* __restrict__ p, long long n)
{
    long long i = (long long)blockIdx.x * blockDim.x + threadIdx.x;
    long long st = (long long)gridDim.x * blockDim.x;
    for (; i < n; i += st) p[i] = 0u;
}

__global__ void f2bf_kernel(const float* __restrict__ in, unsigned short* __restrict__ out,
                            long long n8)
{
    long long i = (long long)blockIdx.x * blockDim.x + threadIdx.x;
    long long st = (long long)gridDim.x * blockDim.x;
    for (; i < n8; i += st) {
        float4 a = *(const float4*)(in + i * 8);
        float4 b = *(const float4*)(in + i * 8 + 4);
        uint4 o;
        o.x = pack2(a.x, a.y); o.y = pack2(a.z, a.w);
        o.z = pack2(b.x, b.y); o.w = pack2(b.z, b.w);
        *(uint4*)(out + i * 8) = o;
    }
}

// ---------------------------------------------------------------------------
// 6 weight matrices (gcn0, gcn1, lin_w[0..3]) fp32 256x256 -> B-frag-linear bf16
// ---------------------------------------------------------------------------
__global__ void wfrag_kernel(const float* __restrict__ g0, const float* __restrict__ g1,
                             const float* __restrict__ lw, unsigned short* __restrict__ out)
{
    int o = blockIdx.x * 256 + threadIdx.x;   // 0..65535
    int mat = blockIdx.y;
    const float* W = (mat == 0) ? g0 : (mat == 1) ? g1 : (lw + (size_t)(mat - 2) * 65536);
    int j = o & 7, lane = (o >> 3) & 63, ks = (o >> 9) & 7, nt = o >> 12;
    int n15 = lane & 15, quad = lane >> 4;
    int k = ks * 32 + quad * 8 + j;
    int n = nt * 16 + n15;
    out[(size_t)mat * 65536 + o] = f2bf(W[(size_t)k * 256 + n]);
}

// ---------------------------------------------------------------------------
// MFMA GEMM: C = A(bf16, Mx256) @ W(bf16 frag-linear) + bias.
// A-staging via global_load_lds (16B) into LINEAR LDS with XOR unit-swizzle
// (unit ^= row&7) applied to BOTH the global source and the LDS read — LDS
// dest stays linear (wave-uniform base + lane*16, HW requirement).
// NOTE: tail stripes read junk rows past M (callers guarantee allocated
// slack); all C/tinv writes are gr<M guarded so junk never escapes.
// Output row: gr*rowMul + z*zRowAdd. If tinvOut != nullptr, also writes
// per-row 1/max(||row||,1e-8) of the bf16-rounded outputs.
// ---------------------------------------------------------------------------
__global__ __launch_bounds__(256, 2)
void gemm_mfma(const unsigned short* __restrict__ A,
               const unsigned short* __restrict__ Wfrag,
               const float* __restrict__ bias,
               unsigned short* __restrict__ Cout,
               int M, int nStripes, int rowMul, int zRowAdd,
               float* __restrict__ tinvOut)
{
    __shared__ unsigned short Asm[64 * 256];   // linear, swizzled content
    __shared__ float rn[64];
    int t = threadIdx.x, w = t >> 6, lane = t & 63;
    int n15 = lane & 15, quad = lane >> 4;
    int z = blockIdx.y;
    Wfrag += (size_t)z * 65536;
    bias  += (size_t)z * 256;

    s16x8 bfr[4][8];
#pragma unroll
    for (int nt = 0; nt < 4; nt++)
#pragma unroll
        for (int ks = 0; ks < 8; ks++)
            bfr[nt][ks] = *(const s16x8*)(Wfrag +
                (size_t)(((w * 4 + nt) * 8 + ks) * 64 + lane) * 8);

    float bcol[4];
#pragma unroll
    for (int nt = 0; nt < 4; nt++) bcol[nt] = bias[(w * 4 + nt) * 16 + n15];

    for (int s = blockIdx.x; s < nStripes; s += gridDim.x) {
        int m0 = s * 64;
        __syncthreads();
#pragma unroll
        for (int i = 0; i < 8; i++) {
            int idx = i * 256 + t;
            int row = idx >> 5, unit = idx & 31;
            const unsigned short* gp = A + (size_t)(m0 + row) * 256
                                       + ((unit ^ (row & 7)) << 3);
            __builtin_amdgcn_global_load_lds(
                (const __attribute__((address_space(1))) void*)gp,
                (__attribute__((address_space(3))) void*)(Asm + ((i * 256 + w * 64) << 3)),
                16, 0, 0);
        }
        __syncthreads();

        f32x4 acc[4][4];
#pragma unroll
        for (int rt = 0; rt < 4; rt++)
#pragma unroll
            for (int nt = 0; nt < 4; nt++)
#pragma unroll
                for (int e = 0; e < 4; e++) acc[rt][nt][e] = 0.f;

#pragma unroll
        for (int rt = 0; rt < 4; rt++) {
            int row = rt * 16 + n15;
            int rbase = row * 256;
            int rx = row & 7;
#pragma unroll
            for (int ks = 0; ks < 8; ks++) {
                int unit = quad + ks * 4;
                s16x8 a = *(const s16x8*)(Asm + rbase + ((unit ^ rx) << 3));
#pragma unroll
                for (int nt = 0; nt < 4; nt++)
                    acc[rt][nt] = __builtin_amdgcn_mfma_f32_16x16x32_bf16(
                        a, bfr[nt][ks], acc[rt][nt], 0, 0, 0);
            }
        }

#pragma unroll
        for (int rt = 0; rt < 4; rt++) {
            int row0 = m0 + rt * 16 + quad * 4;
#pragma unroll
            for (int nt = 0; nt < 4; nt++) {
                int colp = (w * 4 + nt) * 16 + n15;
#pragma unroll
                for (int r = 0; r < 4; r++) {
                    int gr = row0 + r;
                    if (gr < M) {
                        size_t ro = (size_t)gr * rowMul + (size_t)z * zRowAdd;
                        Cout[ro * 256 + colp] = f2bf(acc[rt][nt][r] + bcol[nt]);
                    }
                }
            }
        }

        if (tinvOut) {
            if (t < 64) rn[t] = 0.f;
            __syncthreads();
#pragma unroll
            for (int rt = 0; rt < 4; rt++)
#pragma unroll
                for (int r = 0; r < 4; r++) {
                    float p = 0.f;
#pragma unroll
                    for (int nt = 0; nt < 4; nt++) {
                        uint32 ub = ((uint32)f2bf(acc[rt][nt][r] + bcol[nt])) << 16;
                        float vv = __uint_as_float(ub);
                        p += vv * vv;
                    }
#pragma unroll
                    for (int off = 1; off < 16; off <<= 1) p += __shfl_xor(p, off);
                    if (n15 == 0)
                        atomicAdd(&rn[rt * 16 + quad * 4 + r], p);
                }
            __syncthreads();
            if (t < 64) {
                int gr2 = m0 + t;
                if (gr2 < M) {
                    size_t ro2 = (size_t)gr2 * rowMul + (size_t)z * zRowAdd;
                    tinvOut[ro2] = 1.f / fmaxf(sqrtf(rn[t]), 1e-8f);
                }
            }
        }
    }
}

// ---------------------------------------------------------------------------
// edge counting sort by dst; esorted = (src, dst) pairs in dst order
// ---------------------------------------------------------------------------
__global__ void ehist_kernel(const int* __restrict__ dst, int* __restrict__ ecnt, int E)
{
    for (int e = blockIdx.x * blockDim.x + threadIdx.x; e < E;
         e += gridDim.x * blockDim.x)
        atomicAdd(ecnt + dst[e], 1);
}

__global__ void escatter_kernel(const int* __restrict__ src, const int* __restrict__ dst,
                                const int* __restrict__ eptr, int* __restrict__ efill,
                                uint2* __restrict__ esorted, int E)
{
    for (int e = blockIdx.x * blockDim.x + threadIdx.x; e < E;
         e += gridDim.x * blockDim.x) {
        int d = dst[e];
        int pos = eptr[d] + atomicAdd(efill + d, 1);
        esorted[pos] = make_uint2((uint32)src[e], (uint32)d);
    }
}

// ---------------------------------------------------------------------------
// sim: MFMA diagonal over 16 sorted edges/wave; planar tr (replica planes
// Nn*D apart). All 8 A-fragments preloaded for burst issue.
// ---------------------------------------------------------------------------
__global__ __launch_bounds__(256)
void sim4_kernel(const uint2* __restrict__ esorted,
                 const unsigned short* __restrict__ featb,
                 const unsigned short* __restrict__ tr, const float* __restrict__ tinv,
                 int* __restrict__ bestS, int E, int Nn)
{
    int w = threadIdx.x >> 6, lane = threadIdx.x & 63;
    int n15 = lane & 15, quad = lane >> 4;
    int base = (blockIdx.x * 4 + w) * 16;
    if (base >= E) return;
    int ei = min(base + n15, E - 1);
    uint2 se = esorted[ei];
    const unsigned short* arow = featb + (size_t)se.x * D + quad * 8;
    const unsigned short* brow = tr + (size_t)se.y * D + quad * 8;
    size_t rstride = (size_t)Nn * D;

    s16x8 a[8];
#pragma unroll
    for (int ks = 0; ks < 8; ks++) a[ks] = *(const s16x8*)(arow + ks * 32);

    f32x4 a0 = {0.f, 0.f, 0.f, 0.f}, a1 = a0, a2 = a0, a3 = a0;
#pragma unroll
    for (int ks = 0; ks < 8; ks++) {
        s16x8 b0 = *(const s16x8*)(brow + ks * 32);
        a0 = __builtin_amdgcn_mfma_f32_16x16x32_bf16(a[ks], b0, a0, 0, 0, 0);
    }
#pragma unroll
    for (int ks = 0; ks < 8; ks++) {
        s16x8 b1 = *(const s16x8*)(brow + rstride + ks * 32);
        a1 = __builtin_amdgcn_mfma_f32_16x16x32_bf16(a[ks], b1, a1, 0, 0, 0);
    }
#pragma unroll
    for (int ks = 0; ks < 8; ks++) {
        s16x8 b2 = *(const s16x8*)(brow + 2 * rstride + ks * 32);
        a2 = __builtin_amdgcn_mfma_f32_16x16x32_bf16(a[ks], b2, a2, 0, 0, 0);
    }
#pragma unroll
    for (int ks = 0; ks < 8; ks++) {
        s16x8 b3 = *(const s16x8*)(brow + 3 * rstride + ks * 32);
        a3 = __builtin_amdgcn_mfma_f32_16x16x32_bf16(a[ks], b3, a3, 0, 0, 0);
    }

    if (quad == (n15 >> 2) && base + n15 < E) {
        int r = n15 & 3;
        int d = (int)se.y;
        float v0 = a0[r] * tinv[d];
        float v1 = a1[r] * tinv[Nn + d];
        float v2 = a2[r] * tinv[2 * Nn + d];
        float v3 = a3[r] * tinv[3 * Nn + d];
        float bv = v0; int bi = 0;
        if (v1 > bv) { bv = v1; bi = 1; }   // strict >: first-index ties
        if (v2 > bv) { bv = v2; bi = 2; }
        if (v3 > bv) { bv = v3; bi = 3; }
        bestS[base + n15] = bi;
    }
}

// ---------------------------------------------------------------------------
// unified edge list over SORTED edges (degree histogram only)
// ---------------------------------------------------------------------------
__device__ __forceinline__ void decode_edge(int e, const uint2* __restrict__ esorted,
                                            const int* __restrict__ bestS,
                                            int E, int Nn, int& s, int& d, bool& keep)
{
    if (e < E) {
        uint2 se = esorted[e];
        s = (int)se.x; d = (int)se.y; keep = (s != d);
    } else if (e < 2 * E) {
        int k = e - E;
        uint2 se = esorted[k];
        s = (int)se.x; d = (int)se.y + bestS[k] * Nn; keep = (s != d);
    } else if (e < 2 * E + T * Nn) {
        int k = e - 2 * E; int i = k / Nn; int n = k - i * Nn;
        s = n; d = n + i * Nn; keep = (i != 0);
    } else {
        int v = e - (2 * E + T * Nn); s = v; d = v; keep = true;
    }
}

__global__ void hist_kernel(const uint2* __restrict__ esorted, const int* __restrict__ bestS,
                            int* __restrict__ cnt, int E, int Nn)
{
    int total = 2 * E + (2 * T + 1) * Nn;
    for (int e = blockIdx.x * blockDim.x + threadIdx.x; e < total;
         e += gridDim.x * blockDim.x) {
        int s, d; bool keep;
        decode_edge(e, esorted, bestS, E, Nn, s, d, keep);
        if (keep) atomicAdd(cnt + d, 1);
    }
}

// ---------------------------------------------------------------------------
// merged: dinv for all rows + per-edge packed meta (src | best<<27, dinv[src])
// ---------------------------------------------------------------------------
__global__ void emeta_dinv_kernel(const uint2* __restrict__ esorted,
                                  const int* __restrict__ bestS,
                                  const int* __restrict__ cnt,
                                  float* __restrict__ dinv, uint2* __restrict__ emeta,
                                  int E, int n_total, int work)
{
    for (int i = blockIdx.x * blockDim.x + threadIdx.x; i < work;
         i += gridDim.x * blockDim.x) {
        if (i < n_total) {
            int c = cnt[i];
            dinv[i] = (c > 0) ? rsqrtf((float)c) : 0.f;
        }
        if (i < E) {
            uint2 se = esorted[i];
            uint32 packed = se.x | ((uint32)bestS[i] << 27);
            float dv = rsqrtf((float)cnt[se.x]);
            emeta[i] = make_uint2(packed, __float_as_uint(dv));
        }
    }
}

__global__ void scan_sums(const int* __restrict__ cnt, int* __restrict__ aux, int n)
{
    __shared__ int sd[256];
    int idx = blockIdx.x * 256 + threadIdx.x;
    sd[threadIdx.x] = (idx < n) ? cnt[idx] : 0;
    __syncthreads();
    for (int off = 128; off; off >>= 1) {
        if (threadIdx.x < off) sd[threadIdx.x] += sd[threadIdx.x + off];
        __syncthreads();
    }
    if (threadIdx.x == 0) aux[blockIdx.x] = sd[0];
}

__global__ void scan_aux(const int* __restrict__ aux, int* __restrict__ auxex, int nb)
{
    __shared__ int sd[1024];
    int t = threadIdx.x;
    int v = (t < nb) ? aux[t] : 0;
    sd[t] = v;
    __syncthreads();
    for (int off = 1; off < 1024; off <<= 1) {
        int x = (t >= off) ? sd[t - off] : 0;
        __syncthreads();
        sd[t] += x;
        __syncthreads();
    }
    if (t < nb) auxex[t] = sd[t] - v;
}

__global__ void scan_write(const int* __restrict__ cnt, const int* __restrict__ auxex,
                           int* __restrict__ rowptr, int n)
{
    __shared__ int sd[256];
    int t = threadIdx.x;
    int idx = blockIdx.x * 256 + t;
    int v = (idx < n) ? cnt[idx] : 0;
    sd[t] = v;
    __syncthreads();
    for (int off = 1; off < 256; off <<= 1) {
        int x = (t >= off) ? sd[t - off] : 0;
        __syncthreads();
        sd[t] += x;
        __syncthreads();
    }
    if (idx < n) {
        int rp = auxex[blockIdx.x] + sd[t] - v;
        rowptr[idx] = rp;
        if (idx == n - 1) rowptr[n] = rp + v;
    }
}

// ---------------------------------------------------------------------------
// agg5: one wave per BASE node v, produces all 5 output rows {v, v+iN}.
// xb replica row for node v, replica i: v*xrm + i*xra
// ---------------------------------------------------------------------------
__global__ __launch_bounds__(256)
void agg5_kernel(const int* __restrict__ eptr, const uint2* __restrict__ emeta,
                 const unsigned short* __restrict__ xa,
                 const unsigned short* __restrict__ xb,
                 const float* __restrict__ dinv,
                 unsigned short* __restrict__ outb, int Nn, int xrm, int xra)
{
    int wave = threadIdx.x >> 6, lane = threadIdx.x & 63;
    int v = blockIdx.x * 4 + wave;
    if (v >= Nn) return;

    float dv  = dinv[v];
    float dr1 = dinv[v + Nn];
    float dr2 = dinv[v + 2 * Nn];
    float dr3 = dinv[v + 3 * Nn];
    float dr4 = dinv[v + 4 * Nn];

    uint2 qv = *(const uint2*)(xa + (size_t)v * D + lane * 4);
    qv.x = relu2(qv.x); qv.y = relu2(qv.y);
    float y0 = bflo(qv.x), y1 = bfhi(qv.x), y2 = bflo(qv.y), y3 = bfhi(qv.y);

    float wsb = dv * dv;
    float b0 = wsb * y0, b1 = wsb * y1, b2 = wsb * y2, b3 = wsb * y3;

    float wi1 = dv * dr1, wi2 = dv * dr2, wi3 = dv * dr3;
    float r10 = wi1 * y0, r11 = wi1 * y1, r12 = wi1 * y2, r13 = wi1 * y3;
    float r20 = wi2 * y0, r21 = wi2 * y1, r22 = wi2 * y2, r23 = wi2 * y3;
    float r30 = wi3 * y0, r31 = wi3 * y1, r32 = wi3 * y2, r33 = wi3 * y3;
    float r40 = 0.f, r41 = 0.f, r42 = 0.f, r43 = 0.f;

    {
        uint2 q = *(const uint2*)(xb + ((size_t)v * xrm + 0 * (size_t)xra) * D + lane * 4);
        q.x = relu2(q.x); q.y = relu2(q.y);
        float ws = dr1 * dr1;
        r10 = fmaf(ws, bflo(q.x), r10); r11 = fmaf(ws, bfhi(q.x), r11);
        r12 = fmaf(ws, bflo(q.y), r12); r13 = fmaf(ws, bfhi(q.y), r13);
    }
    {
        uint2 q = *(const uint2*)(xb + ((size_t)v * xrm + 1 * (size_t)xra) * D + lane * 4);
        q.x = relu2(q.x); q.y = relu2(q.y);
        float ws = dr2 * dr2;
        r20 = fmaf(ws, bflo(q.x), r20); r21 = fmaf(ws, bfhi(q.x), r21);
        r22 = fmaf(ws, bflo(q.y), r22); r23 = fmaf(ws, bfhi(q.y), r23);
    }
    {
        uint2 q = *(const uint2*)(xb + ((size_t)v * xrm + 2 * (size_t)xra) * D + lane * 4);
        q.x = relu2(q.x); q.y = relu2(q.y);
        float ws = dr3 * dr3;
        r30 = fmaf(ws, bflo(q.x), r30); r31 = fmaf(ws, bfhi(q.x), r31);
        r32 = fmaf(ws, bflo(q.y), r32); r33 = fmaf(ws, bfhi(q.y), r33);
    }
    {
        uint2 q = *(const uint2*)(xb + ((size_t)v * xrm + 3 * (size_t)xra) * D + lane * 4);
        q.x = relu2(q.x); q.y = relu2(q.y);
        float ws = dr4 * dr4;
        r40 = fmaf(ws, bflo(q.x), r40); r41 = fmaf(ws, bfhi(q.x), r41);
        r42 = fmaf(ws, bflo(q.y), r42); r43 = fmaf(ws, bfhi(q.y), r43);
    }

    int j = eptr[v], jend = eptr[v + 1];

#define EDGE_META(mm, ssu, wws)                                                    \
    uint32 ssu = (uint32)__builtin_amdgcn_readfirstlane((int)mm.x);                \
    float wws = __uint_as_float((uint32)__builtin_amdgcn_readfirstlane((int)mm.y));

#define EDGE_BODY(qq, ss, bb, ww)                                                  \
    {                                                                              \
        float x0 = bflo(qq.x), x1 = bfhi(qq.x), x2 = bflo(qq.y), x3 = bfhi(qq.y);  \
        float wb = (ss != v) ? (ww) * dv : 0.f;                                    \
        if (bb == 0) wb += wb;                                                     \
        b0 = fmaf(wb, x0, b0); b1 = fmaf(wb, x1, b1);                              \
        b2 = fmaf(wb, x2, b2); b3 = fmaf(wb, x3, b3);                              \
        if (bb == 1) {                                                             \
            float wr = (ww) * dr1;                                                 \
            r10 = fmaf(wr, x0, r10); r11 = fmaf(wr, x1, r11);                      \
            r12 = fmaf(wr, x2, r12); r13 = fmaf(wr, x3, r13);                      \
        } else if (bb == 2) {                                                      \
            float wr = (ww) * dr2;                                                 \
            r20 = fmaf(wr, x0, r20); r21 = fmaf(wr, x1, r21);                      \
            r22 = fmaf(wr, x2, r22); r23 = fmaf(wr, x3, r23);                      \
        } else if (bb == 3) {                                                      \
            float wr = (ww) * dr3;                                                 \
            r30 = fmaf(wr, x0, r30); r31 = fmaf(wr, x1, r31);                      \
            r32 = fmaf(wr, x2, r32); r33 = fmaf(wr, x3, r33);                      \
        }                                                                          \
    }

    for (; j + 4 <= jend; j += 4) {
        uint2 m0 = emeta[j];
        uint2 m1 = emeta[j + 1];
        uint2 m2 = emeta[j + 2];
        uint2 m3 = emeta[j + 3];
        EDGE_META(m0, su0, ws0); EDGE_META(m1, su1, ws1);
        EDGE_META(m2, su2, ws2); EDGE_META(m3, su3, ws3);
        int s0 = (int)(su0 & 0x07FFFFFFu), bx0 = (int)(su0 >> 27);
        int s1 = (int)(su1 & 0x07FFFFFFu), bx1 = (int)(su1 >> 27);
        int s2 = (int)(su2 & 0x07FFFFFFu), bx2 = (int)(su2 >> 27);
        int s3 = (int)(su3 & 0x07FFFFFFu), bx3 = (int)(su3 >> 27);
        uint2 q0 = *(const uint2*)(xa + (size_t)s0 * D + lane * 4);
        uint2 q1 = *(const uint2*)(xa + (size_t)s1 * D + lane * 4);
        uint2 q2 = *(const uint2*)(xa + (size_t)s2 * D + lane * 4);
        uint2 q3 = *(const uint2*)(xa + (size_t)s3 * D + lane * 4);
        q0.x = relu2(q0.x); q0.y = relu2(q0.y);
        q1.x = relu2(q1.x); q1.y = relu2(q1.y);
        q2.x = relu2(q2.x); q2.y = relu2(q2.y);
        q3.x = relu2(q3.x); q3.y = relu2(q3.y);
        EDGE_BODY(q0, s0, bx0, ws0);
        EDGE_BODY(q1, s1, bx1, ws1);
        EDGE_BODY(q2, s2, bx2, ws2);
        EDGE_BODY(q3, s3, bx3, ws3);
    }
    for (; j + 2 <= jend; j += 2) {
        uint2 m0 = emeta[j];
        uint2 m1 = emeta[j + 1];
        EDGE_META(m0, su0, ws0); EDGE_META(m1, su1, ws1);
        int s0 = (int)(su0 & 0x07FFFFFFu), bx0 = (int)(su0 >> 27);
        int s1 = (int)(su1 & 0x07FFFFFFu), bx1 = (int)(su1 >> 27);
        uint2 q0 = *(const uint2*)(xa + (size_t)s0 * D + lane * 4);
        uint2 q1 = *(const uint2*)(xa + (size_t)s1 * D + lane * 4);
        q0.x = relu2(q0.x); q0.y = relu2(q0.y);
        q1.x = relu2(q1.x); q1.y = relu2(q1.y);
        EDGE_BODY(q0, s0, bx0, ws0);
        EDGE_BODY(q1, s1, bx1, ws1);
    }
    if (j < jend) {
        uint2 m0 = emeta[j];
        EDGE_META(m0, su0, ws0);
        int s0 = (int)(su0 & 0x07FFFFFFu), bx0 = (int)(su0 >> 27);
        uint2 q0 = *(const uint2*)(xa + (size_t)s0 * D + lane * 4);
        q0.x = relu2(q0.x); q0.y = relu2(q0.y);
        EDGE_BODY(q0, s0, bx0, ws0);
    }
#undef EDGE_BODY
#undef EDGE_META

    uint2 o;
    o.x = pack2(b0, b1); o.y = pack2(b2, b3);
    *(uint2*)(outb + (size_t)v * D + lane * 4) = o;
    o.x = pack2(r10, r11); o.y = pack2(r12, r13);
    *(uint2*)(outb + ((size_t)v + Nn) * D + lane * 4) = o;
    o.x = pack2(r20, r21); o.y = pack2(r22, r23);
    *(uint2*)(outb + ((size_t)v + 2 * (size_t)Nn) * D + lane * 4) = o;
    o.x = pack2(r30, r31); o.y = pack2(r32, r33);
    *(uint2*)(outb + ((size_t)v + 3 * (size_t)Nn) * D + lane * 4) = o;
    o.x = pack2(r40, r41); o.y = pack2(r42, r43);
    *(uint2*)(outb + ((size_t)v + 4 * (size_t)Nn) * D + lane * 4) = o;
}

// ---------------------------------------------------------------------------
// MFMA logits + fused argmax + H
// ---------------------------------------------------------------------------
__global__ __launch_bounds__(256, 2)
void logits_mfma(const unsigned short* __restrict__ af2, const float* __restrict__ Wl,
                 const float* __restrict__ bl, float* __restrict__ H,
                 int M, int Nn, int nStripes)
{
    __shared__ unsigned short Asm[64 * 264];
    int t = threadIdx.x, w = t >> 6, lane = t & 63;
    int n15 = lane & 15, quad = lane >> 4;

    s16x8 bfr[4][8];
#pragma unroll
    for (int nt = 0; nt < 4; nt++)
#pragma unroll
        for (int ks = 0; ks < 8; ks++) {
            s16x8 f;
#pragma unroll
            for (int j = 0; j < 8; j++) {
                int k = ks * 32 + quad * 8 + j;
                f[j] = (short)f2bf(Wl[(size_t)k * NS + nt * 16 + n15]);
            }
            bfr[nt][ks] = f;
        }
    float bcol[4];
#pragma unroll
    for (int nt = 0; nt < 4; nt++) bcol[nt] = bl[nt * 16 + n15];

    for (int s = blockIdx.x; s < nStripes; s += gridDim.x) {
        int m0 = s * 64;
        __syncthreads();
#pragma unroll
        for (int i = 0; i < 8; i++) {
            int idx = i * 256 + t;
            int m = idx >> 5, kc = (idx & 31) * 8;
            int gm = m0 + m;
            uint4 v = make_uint4(0u, 0u, 0u, 0u);
            if (gm < M) {
                v = *(const uint4*)(af2 + (size_t)gm * 256 + kc);
                v.x = relu2(v.x); v.y = relu2(v.y);
                v.z = relu2(v.z); v.w = relu2(v.w);
            }
            *(uint4*)(Asm + m * 264 + kc) = v;
        }
        __syncthreads();

        f32x4 acc[4];
#pragma unroll
        for (int nt = 0; nt < 4; nt++)
#pragma unroll
            for (int e = 0; e < 4; e++) acc[nt][e] = 0.f;

        int abase = (w * 16 + n15) * 264 + quad * 8;
#pragma unroll
        for (int ks = 0; ks < 8; ks++) {
            s16x8 a = *(const s16x8*)(Asm + abase + ks * 32);
#pragma unroll
            for (int nt = 0; nt < 4; nt++)
                acc[nt] = __builtin_amdgcn_mfma_f32_16x16x32_bf16(
                    a, bfr[nt][ks], acc[nt], 0, 0, 0);
        }

#pragma unroll
        for (int e = 0; e < 4; e++) {
            float bv = acc[0][e] + bcol[0]; int bi = n15;
#pragma unroll
            for (int nt = 1; nt < 4; nt++) {
                float v = acc[nt][e] + bcol[nt];
                int c = nt * 16 + n15;
                if (v > bv) { bv = v; bi = c; }
            }
#pragma unroll
            for (int off = 1; off < 16; off <<= 1) {
                float ov = __shfl_xor(bv, off);
                int   oi = __shfl_xor(bi, off);
                if (ov > bv || (ov == bv && oi < bi)) { bv = ov; bi = oi; }
            }
            if (n15 == 0) {
                int gr = m0 + w * 16 + quad * 4 + e;
                if (gr < M) atomicAdd(H + (size_t)(gr % Nn) * NS + bi, 1.0f);
            }
        }
    }
}

// ---------------------------------------------------------------------------
// maskTb: H (Nn x NS fp32) -> bf16 maskT [NS][Kpad] (1.0 where H>0, else 0),
// zero-padded in [Nn, Kpad). LDS-tiled transpose, coalesced both sides.
// ---------------------------------------------------------------------------
__global__ __launch_bounds__(256)
void maskTb_kernel(const float* __restrict__ H, unsigned short* __restrict__ maskTb,
                   int Nn, int Kpad)
{
    __shared__ unsigned short tile[64 * 72];   // [c][n], pad 72
    int t = threadIdx.x;
    int n0 = blockIdx.x * 64;
    int c = t & 63, rr = t >> 6;
#pragma unroll
    for (int i = 0; i < 16; i++) {
        int n = rr + i * 4;
        float hv = (n0 + n < Nn) ? H[(size_t)(n0 + n) * NS + c] : 0.f;
        tile[c * 72 + n] = (hv > 0.f) ? (unsigned short)0x3F80 : (unsigned short)0;
    }
    __syncthreads();
#pragma unroll
    for (int i = 0; i < 2; i++) {
        int idx = i * 256 + t;              // 0..511: 64 rows x 8 chunks
        int cc = idx >> 3, ch = idx & 7;
        uint4 v = *(const uint4*)(tile + cc * 72 + ch * 8);
        *(uint4*)(maskTb + (size_t)cc * Kpad + n0 + ch * 8) = v;
    }
}

// ---------------------------------------------------------------------------
// he_gemm: he = maskTb (64 x Kpad bf16) @ af2 (Kpad x 256 bf16), split-K.
// ---------------------------------------------------------------------------
__global__ __launch_bounds__(256, 2)
void he_gemm(const unsigned short* __restrict__ maskTb,
             const unsigned short* __restrict__ af2,
             float* __restrict__ partials, int Kpad)
{
    __shared__ unsigned short Bsm[32 * 264];
    int t = threadIdx.x, w = t >> 6, lane = t & 63;
    int n15 = lane & 15, quad = lane >> 4;
    int k0 = blockIdx.x * 256;

    f32x4 acc[4][4];
#pragma unroll
    for (int mt = 0; mt < 4; mt++)
#pragma unroll
        for (int nt = 0; nt < 4; nt++)
#pragma unroll
            for (int e = 0; e < 4; e++) acc[mt][nt][e] = 0.f;

    for (int s = 0; s < 8; s++) {
        int k = k0 + s * 32;
        __syncthreads();
#pragma unroll
        for (int i = 0; i < 4; i++) {
            int idx = i * 256 + t;              // 0..1023: 32 rows x 32 chunks
            int row = idx >> 5, col8 = (idx & 31) * 8;
            uint4 v = *(const uint4*)(af2 + (size_t)(k + row) * 256 + col8);
            *(uint4*)(Bsm + row * 264 + col8) = v;
        }
        __syncthreads();

        s16x8 a[4];
#pragma unroll
        for (int mt = 0; mt < 4; mt++)
            a[mt] = *(const s16x8*)(maskTb + (size_t)(mt * 16 + n15) * Kpad
                                    + k + quad * 8);
#pragma unroll
        for (int nt = 0; nt < 4; nt++) {
            int ncol = w * 64 + nt * 16 + n15;
            s16x8 b;
#pragma unroll
            for (int j = 0; j < 8; j++)
                b[j] = (short)Bsm[(quad * 8 + j) * 264 + ncol];
#pragma unroll
            for (int mt = 0; mt < 4; mt++)
                acc[mt][nt] = __builtin_amdgcn_mfma_f32_16x16x32_bf16(
                    a[mt], b, acc[mt][nt], 0, 0, 0);
        }
    }

    float* pdst = partials + (size_t)blockIdx.x * (64 * 256);
#pragma unroll
    for (int mt = 0; mt < 4; mt++)
#pragma unroll
        for (int nt = 0; nt < 4; nt++)
#pragma unroll
            for (int r = 0; r < 4; r++) {
                int m = mt * 16 + quad * 4 + r;
                int n = w * 64 + nt * 16 + n15;
                pdst[(size_t)m * 256 + n] = acc[mt][nt][r];
            }
}

// ---------------------------------------------------------------------------
// he_reduce2: out_he[c][f] = sum_b partials[b][c][f]  (plain store)
// ---------------------------------------------------------------------------
__global__ __launch_bounds__(256)
void he_reduce2(const float* __restrict__ partials, float* __restrict__ he, int KB)
{
    int idx = blockIdx.x * 256 + threadIdx.x;   // 0..16383
    float s = 0.f;
    for (int b = 0; b < KB; b++)
        s += partials[(size_t)b * 16384 + idx];
    he[idx] = s;
}

// ---------------------------------------------------------------------------
__global__ void bigb_copy(const float* __restrict__ he, float* __restrict__ BigB)
{
    int idx = blockIdx.x * 256 + threadIdx.x;
    if (idx < D * NS) {
        int d = idx >> 6, c = idx & 63;
        BigB[idx] = he[(size_t)c * D + d];
    }
}

__global__ __launch_bounds__(256)
void bigb_mm(const float* __restrict__ lin_w, const float* __restrict__ lin_b,
             const float* __restrict__ he, float* __restrict__ BigB,
             float* __restrict__ beta)
{
    int gw = (int)((blockIdx.x * 256 + threadIdx.x) >> 6);
    int lane = threadIdx.x & 63;
    const int totalA = T * D * NS;
    if (gw >= totalA + T * NS) return;
    const float* xrow; const float* hrow; float* outp;
    if (gw < totalA) {
        int t = gw / (D * NS); int rem = gw - t * D * NS;
        int d = rem / NS; int c = rem - d * NS;
        xrow = lin_w + ((size_t)t * D + d) * D;
        hrow = he + (size_t)c * D;
        outp = BigB + ((size_t)(t + 1) * D + d) * NS + c;
    } else {
        int i = gw - totalA; int t = i / NS; int c = i - t * NS;
        xrow = lin_b + (size_t)t * D;
        hrow = he + (size_t)c * D;
        outp = beta + (size_t)(t + 1) * NS + c;
    }
    float4 x = *(const float4*)(xrow + lane * 4);
    float4 h = *(const float4*)(hrow + lane * 4);
    float s = x.x * h.x + x.y * h.y + x.z * h.z + x.w * h.w;
#pragma unroll
    for (int off = 32; off; off >>= 1) s += __shfl_xor(s, off);
    if (lane == 0) *outp = s;
}

// ---------------------------------------------------------------------------
// MFMA dots: A-rows from featb (bf16, useBf=1, must NOT alias dots) or
// staged fp32 feat (useBf=0). grid (nBlk, 5)
// ---------------------------------------------------------------------------
__global__ __launch_bounds__(256, 2)
void dots_mfma(const unsigned short* __restrict__ featb,
               const float* __restrict__ feat32, int useBf,
               const float* __restrict__ BigB,
               const float* __restrict__ beta, float* __restrict__ dots,
               int Nn, int nStripes)
{
    __shared__ unsigned short Asm[64 * 264];
    int t = threadIdx.x, w = t >> 6, lane = t & 63;
    int n15 = lane & 15, quad = lane >> 4;
    int rho = blockIdx.y;
    const float* Bp = BigB + (size_t)rho * D * NS;

    s16x8 bfr[4][8];
#pragma unroll
    for (int nt = 0; nt < 4; nt++)
#pragma unroll
        for (int ks = 0; ks < 8; ks++) {
            s16x8 f;
#pragma unroll
            for (int j = 0; j < 8; j++) {
                int k = ks * 32 + quad * 8 + j;
                f[j] = (short)f2bf(Bp[(size_t)k * NS + nt * 16 + n15]);
            }
            bfr[nt][ks] = f;
        }
    float bcol[4];
#pragma unroll
    for (int nt = 0; nt < 4; nt++) bcol[nt] = beta[rho * NS + nt * 16 + n15];

    for (int s = blockIdx.x; s < nStripes; s += gridDim.x) {
        int m0 = s * 64;
        __syncthreads();
#pragma unroll
        for (int i = 0; i < 8; i++) {
            int idx = i * 256 + t;
            int m = idx >> 5, kc = (idx & 31) * 8;
            int gm = m0 + m;
            uint4 o = make_uint4(0u, 0u, 0u, 0u);
            if (gm < Nn) {
                if (useBf) {
                    o = *(const uint4*)(featb + (size_t)gm * 256 + kc);
                } else {
                    float4 a = *(const float4*)(feat32 + (size_t)gm * 256 + kc);
                    float4 b = *(const float4*)(feat32 + (size_t)gm * 256 + kc + 4);
                    o.x = pack2(a.x, a.y); o.y = pack2(a.z, a.w);
                    o.z = pack2(b.x, b.y); o.w = pack2(b.z, b.w);
                }
            }
            *(uint4*)(Asm + m * 264 + kc) = o;
        }
        __syncthreads();

        f32x4 acc[4];
#pragma unroll
        for (int nt = 0; nt < 4; nt++)
#pragma unroll
            for (int e = 0; e < 4; e++) acc[nt][e] = 0.f;

        int abase = (w * 16 + n15) * 264 + quad * 8;
#pragma unroll
        for (int ks = 0; ks < 8; ks++) {
            s16x8 a = *(const s16x8*)(Asm + abase + ks * 32);
#pragma unroll
            for (int nt = 0; nt < 4; nt++)
                acc[nt] = __builtin_amdgcn_mfma_f32_16x16x32_bf16(
                    a, bfr[nt][ks], acc[nt], 0, 0, 0);
        }

#pragma unroll
        for (int e = 0; e < 4; e++) {
            int gr = m0 + w * 16 + quad * 4 + e;
            if (gr >= Nn) continue;
#pragma unroll
            for (int nt = 0; nt < 4; nt++) {
                int c = nt * 16 + n15;
                dots[((size_t)rho * Nn + gr) * NS + c] = (acc[nt][e] + bcol[nt]) * 0.0625f;
            }
        }
    }
}

// ---------------------------------------------------------------------------
extern "C" void kernel_launch(void* const* d_in, const int* in_sizes, int n_in,
                              void* d_out, int out_size, void* d_ws, size_t ws_size,
                              hipStream_t stream)
{
    const int*   edge_index = (const int*)d_in[0];
    const float* features   = (const float*)d_in[1];
    const float* lin_w      = (const float*)d_in[2];
    const float* lin_b      = (const float*)d_in[3];
    const float* gcn0_w     = (const float*)d_in[4];
    const float* gcn0_b     = (const float*)d_in[5];
    const float* gcn1_w     = (const float*)d_in[6];
    const float* gcn1_b     = (const float*)d_in[7];
    const float* lin1_w     = (const float*)d_in[8];
    const float* lin1_b     = (const float*)d_in[9];

    int E  = in_sizes[0] / 2;
    int Nn = in_sizes[1] / D;
    int n_total = (T + 1) * Nn;
    int Mrep = T * Nn;

    const int* src = edge_index;
    const int* dst = edge_index + E;

    float* out_H    = (float*)d_out;
    float* out_he   = out_H + (size_t)Nn * NS;
    float* out_dots = out_he + (size_t)NS * D;

    // he GEMM split-K geometry
    int KB   = (Nn + 255) / 256;      // blocks, 256 K per block
    int Kpad = KB * 256;

    // ---- ws carve: two big bf16 regions + BigB (+ featb if it fits)
    char* ws0 = (char*)d_ws;
    char* wsp = ws0;
    auto carve = [&](size_t bytes) {
        char* p = wsp; wsp += (bytes + 255) & ~(size_t)255; return p;
    };
    unsigned short* R1   = (unsigned short*)carve((size_t)n_total * D * 2);
    unsigned short* R2   = (unsigned short*)carve((size_t)n_total * D * 2);
    float*          BigB = (float*)carve((size_t)(T + 1) * D * NS * 4);
    float*          beta = (float*)carve((size_t)(T + 1) * NS * 4);
    unsigned short* transformed = R2;   // planar prefix of R2 (T*Nn rows)

    // featb: prefer ws (safe to read during dots_mfma); fall back to the
    // out_dots scratch region + fp32 staging in dots_mfma. +32KB slack for
    // gemm tail-stripe over-read (global_load_lds reads past M).
    size_t featb_bytes = (size_t)Nn * D * 2 + 64 * 512;
    unsigned short* featb = nullptr;
    int useBfDots = 0;
    if ((size_t)(wsp - ws0) + featb_bytes + 256 <= ws_size) {
        featb = (unsigned short*)carve(featb_bytes);
        useBfDots = 1;
    }

    // ---- scratch in the out_dots region (dead before dots_mfma)
    char* sc = (char*)out_dots;
    auto carve2 = [&](size_t bytes) {
        char* p = sc; sc += (bytes + 255) & ~(size_t)255; return p;
    };
    float* tinv    = (float*)carve2((size_t)Mrep * 4);
    int*   best    = (int*)carve2((size_t)E * 4);       // SORTED order
    // cnt / ecnt / efill contiguous -> single zero launch
    int*   cnt     = (int*)carve2((size_t)(n_total + 2 * Nn) * 4);
    int*   ecnt    = cnt + n_total;
    int*   efill   = ecnt + Nn;
    float* dinv    = (float*)carve2((size_t)n_total * 4);
    int*   aux     = (int*)carve2(1024 * 4);
    int*   auxex   = (int*)carve2(1024 * 4);
    if (!featb) featb = (unsigned short*)carve2(featb_bytes);
    unsigned short* Wfrags = (unsigned short*)carve2((size_t)6 * 65536 * 2);
    int*   eptr    = (int*)carve2((size_t)(Nn + 1) * 4);
    uint2* esorted = (uint2*)carve2((size_t)E * 8);     // (src, dst) in dst order
    uint2* emeta   = (uint2*)carve2((size_t)E * 8);     // (src|best<<27, dinv[src])
    unsigned short* maskTb = (unsigned short*)carve2((size_t)NS * Kpad * 2);

    // he_gemm partials live in R1 (dead after layer-1 agg): KB*64KB ~ 12.8MB
    float* partials = (float*)R1;

    // ---- zero accumulators (merged: cnt+ecnt+efill in one shot)
    zero_kernel<<<512, 256, 0, stream>>>((uint32*)cnt, (long long)(n_total + 2 * Nn));
    zero_kernel<<<512, 256, 0, stream>>>((uint32*)out_H, (long long)Nn * NS + NS * D);
    zero_kernel<<<1, 256, 0, stream>>>((uint32*)beta, (T + 1) * NS);

    // 0. conversions
    wfrag_kernel<<<dim3(256, 6), 256, 0, stream>>>(gcn0_w, gcn1_w, lin_w, Wfrags);
    f2bf_kernel<<<2048, 256, 0, stream>>>(features, featb, (long long)Nn * D / 8);

    // 1. transformed[z*Nn + n] = featb[n] @ lin_w[z] + lin_b[z], fused row norms
    int strN = (Nn + 63) / 64;
    gemm_mfma<<<dim3(512, T), 256, 0, stream>>>(featb, Wfrags + 2 * 65536, lin_b,
                                                transformed, Nn, strN, 1, Nn, tinv);

    // 2. edge sort by dst + MFMA-diagonal sim
    ehist_kernel<<<2048, 256, 0, stream>>>(dst, ecnt, E);
    int enb = (Nn + 255) / 256;
    scan_sums<<<enb, 256, 0, stream>>>(ecnt, aux, Nn);
    scan_aux<<<1, 1024, 0, stream>>>(aux, auxex, enb);
    scan_write<<<enb, 256, 0, stream>>>(ecnt, auxex, eptr, Nn);
    escatter_kernel<<<2048, 256, 0, stream>>>(src, dst, eptr, efill, esorted, E);
    int nGroups = (E + 15) / 16;
    sim4_kernel<<<(nGroups + 3) / 4, 256, 0, stream>>>(esorted, featb, transformed,
                                                       tinv, best, E, Nn);

    // 3. degrees -> dinv + packed per-edge meta (merged)
    hist_kernel<<<2048, 256, 0, stream>>>(esorted, best, cnt, E, Nn);
    int work = (E > n_total) ? E : n_total;
    emeta_dinv_kernel<<<2048, 256, 0, stream>>>(esorted, best, cnt, dinv, emeta,
                                                E, n_total, work);

    // 4. layer 0 (xb = transformed, planar replica planes)
    int strT = (n_total + 63) / 64;
    agg5_kernel<<<(Nn + 3) / 4, 256, 0, stream>>>(eptr, emeta, featb, transformed,
                                                  dinv, R1, Nn, 1, Nn);
    gemm_mfma<<<dim3(512, 1), 256, 0, stream>>>(R1, Wfrags, gcn0_b, R1, n_total,
                                                strT, 1, 0, nullptr);

    // 5. layer 1 (xb = R1 planar replicas)
    agg5_kernel<<<(Nn + 3) / 4, 256, 0, stream>>>(eptr, emeta, R1, R1 + (size_t)Nn * D,
                                                  dinv, R2, Nn, 1, Nn);
    gemm_mfma<<<dim3(512, 1), 256, 0, stream>>>(R2, Wfrags + 65536, gcn1_b, R2,
                                                n_total, strT, 1, 0, nullptr);

    // 6. classes + H (MFMA + fused argmax)
    logits_mfma<<<512, 256, 0, stream>>>(R2, lin1_w, lin1_b, out_H, n_total, Nn, strT);

    // 7. hyperedge features as a mask GEMM: maskT build + split-K MFMA + reduce
    maskTb_kernel<<<Kpad / 64, 256, 0, stream>>>(out_H, maskTb, Nn, Kpad);
    he_gemm<<<KB, 256, 0, stream>>>(maskTb, R2, partials, Kpad);
    he_reduce2<<<64, 256, 0, stream>>>(partials, out_he, KB);

    // 8. dots (MFMA over 5 rho)
    bigb_copy<<<(D * NS + 255) / 256, 256, 0, stream>>>(out_he, BigB);
    bigb_mm<<<(T * D * NS + T * NS + 3) / 4, 256, 0, stream>>>(lin_w, lin_b, out_he,
                                                               BigB, beta);
    dots_mfma<<<dim3(160, 5), 256, 0, stream>>>(featb, features, useBfDots,
                                                BigB, beta, out_dots, Nn, strN);
}

// Round 12
// 915.154 us; speedup vs baseline: 1.1098x; 1.0327x over previous
//
#include <hip/hip_runtime.h>

#define D 256
#define T 4
#define NS 64

typedef unsigned int uint32;
typedef short s16x8 __attribute__((ext_vector_type(8)));
typedef float f32x4 __attribute__((ext_vector_type(4)));

// ---- bf16 helpers (manual RNE) --------------------------------------------
__device__ __forceinline__ float bflo(uint32 u) { return __uint_as_float(u << 16); }
__device__ __forceinline__ float bfhi(uint32 u) { return __uint_as_float(u & 0xffff0000u); }
__device__ __forceinline__ unsigned short f2bf(float x) {
    uint32 u = __float_as_uint(x);
    u = u + 0x7FFFu + ((u >> 16) & 1u);
    return (unsigned short)(u >> 16);
}
__device__ __forceinline__ uint32 pack2(float a, float b) {
    return (uint32)f2bf(a) | ((uint32)f2bf(b) << 16);
}
// relu on 2 packed bf16
__device__ __forceinline__ uint32 relu2(uint32 u) {
    uint32 s = u & 0x80008000u;
    uint32 m = ((s >> 15) ^ 0x00010001u) * 0xFFFFu;
    return u & m;
}
// relu on an s16x8 fragment (4 packed dwords)
__device__ __forceinline__ s16x8 relu8(s16x8 a) {
    uint32* p = (uint32*)&a;
    p[0] = relu2(p[0]); p[1] = relu2(p[1]);
    p[2] = relu2(p[2]); p[3] = relu2(p[3]);
    return a;
}

// ---------------------------------------------------------------------------
__global__ void zero_kernel(uint32* __restrict__ p, long long n)
{
    long long i = (long long)blockIdx.x * blockDim.x + threadIdx.x;
    long long st = (long long)gridDim.x * blockDim.x;
    for (; i < n; i += st) p[i] = 0u;
}

__global__ void f2bf_kernel(const float* __restrict__ in, unsigned short* __restrict__ out,
                            long long n8)
{
    long long i = (long long)blockIdx.x * blockDim.x + threadIdx.x;
    long long st = (long long)gridDim.x * blockDim.x;
    for (; i < n8; i += st) {
        float4 a = *(const float4*)(in + i * 8);
        float4 b = *(const float4*)(in + i * 8 + 4);
        uint4 o;
        o.x = pack2(a.x, a.y); o.y = pack2(a.z, a.w);
        o.z = pack2(b.x, b.y); o.w = pack2(b.z, b.w);
        *(uint4*)(out + i * 8) = o;
    }
}

// ---------------------------------------------------------------------------
// 6 weight matrices (gcn0, gcn1, lin_w[0..3]) fp32 256x256 -> B-frag-linear bf16
// ---------------------------------------------------------------------------
__global__ void wfrag_kernel(const float* __restrict__ g0, const float* __restrict__ g1,
                             const float* __restrict__ lw, unsigned short* __restrict__ out)
{
    int o = blockIdx.x * 256 + threadIdx.x;   // 0..65535
    int mat = blockIdx.y;
    const float* W = (mat == 0) ? g0 : (mat == 1) ? g1 : (lw + (size_t)(mat - 2) * 65536);
    int j = o & 7, lane = (o >> 3) & 63, ks = (o >> 9) & 7, nt = o >> 12;
    int n15 = lane & 15, quad = lane >> 4;
    int k = ks * 32 + quad * 8 + j;
    int n = nt * 16 + n15;
    out[(size_t)mat * 65536 + o] = f2bf(W[(size_t)k * 256 + n]);
}

// ---------------------------------------------------------------------------
// MFMA GEMM: C = A(bf16, Mx256) @ W(bf16 frag-linear) + bias.
// A-staging via global_load_lds (16B) into LINEAR LDS with XOR unit-swizzle
// (unit ^= row&7) applied to BOTH the global source and the LDS read.
// Tail stripes read junk rows past M (callers guarantee allocated slack);
// all C/tinv writes gr<M guarded.
// ---------------------------------------------------------------------------
__global__ __launch_bounds__(256, 2)
void gemm_mfma(const unsigned short* __restrict__ A,
               const unsigned short* __restrict__ Wfrag,
               const float* __restrict__ bias,
               unsigned short* __restrict__ Cout,
               int M, int nStripes, int rowMul, int zRowAdd,
               float* __restrict__ tinvOut)
{
    __shared__ unsigned short Asm[64 * 256];   // linear, swizzled content
    __shared__ float rn[64];
    int t = threadIdx.x, w = t >> 6, lane = t & 63;
    int n15 = lane & 15, quad = lane >> 4;
    int z = blockIdx.y;
    Wfrag += (size_t)z * 65536;
    bias  += (size_t)z * 256;

    s16x8 bfr[4][8];
#pragma unroll
    for (int nt = 0; nt < 4; nt++)
#pragma unroll
        for (int ks = 0; ks < 8; ks++)
            bfr[nt][ks] = *(const s16x8*)(Wfrag +
                (size_t)(((w * 4 + nt) * 8 + ks) * 64 + lane) * 8);

    float bcol[4];
#pragma unroll
    for (int nt = 0; nt < 4; nt++) bcol[nt] = bias[(w * 4 + nt) * 16 + n15];

    for (int s = blockIdx.x; s < nStripes; s += gridDim.x) {
        int m0 = s * 64;
        __syncthreads();
#pragma unroll
        for (int i = 0; i < 8; i++) {
            int idx = i * 256 + t;
            int row = idx >> 5, unit = idx & 31;
            const unsigned short* gp = A + (size_t)(m0 + row) * 256
                                       + ((unit ^ (row & 7)) << 3);
            __builtin_amdgcn_global_load_lds(
                (const __attribute__((address_space(1))) void*)gp,
                (__attribute__((address_space(3))) void*)(Asm + ((i * 256 + w * 64) << 3)),
                16, 0, 0);
        }
        __syncthreads();

        f32x4 acc[4][4];
#pragma unroll
        for (int rt = 0; rt < 4; rt++)
#pragma unroll
            for (int nt = 0; nt < 4; nt++)
#pragma unroll
                for (int e = 0; e < 4; e++) acc[rt][nt][e] = 0.f;

#pragma unroll
        for (int rt = 0; rt < 4; rt++) {
            int row = rt * 16 + n15;
            int rbase = row * 256;
            int rx = row & 7;
#pragma unroll
            for (int ks = 0; ks < 8; ks++) {
                int unit = quad + ks * 4;
                s16x8 a = *(const s16x8*)(Asm + rbase + ((unit ^ rx) << 3));
#pragma unroll
                for (int nt = 0; nt < 4; nt++)
                    acc[rt][nt] = __builtin_amdgcn_mfma_f32_16x16x32_bf16(
                        a, bfr[nt][ks], acc[rt][nt], 0, 0, 0);
            }
        }

#pragma unroll
        for (int rt = 0; rt < 4; rt++) {
            int row0 = m0 + rt * 16 + quad * 4;
#pragma unroll
            for (int nt = 0; nt < 4; nt++) {
                int colp = (w * 4 + nt) * 16 + n15;
#pragma unroll
                for (int r = 0; r < 4; r++) {
                    int gr = row0 + r;
                    if (gr < M) {
                        size_t ro = (size_t)gr * rowMul + (size_t)z * zRowAdd;
                        Cout[ro * 256 + colp] = f2bf(acc[rt][nt][r] + bcol[nt]);
                    }
                }
            }
        }

        if (tinvOut) {
            if (t < 64) rn[t] = 0.f;
            __syncthreads();
#pragma unroll
            for (int rt = 0; rt < 4; rt++)
#pragma unroll
                for (int r = 0; r < 4; r++) {
                    float p = 0.f;
#pragma unroll
                    for (int nt = 0; nt < 4; nt++) {
                        uint32 ub = ((uint32)f2bf(acc[rt][nt][r] + bcol[nt])) << 16;
                        float vv = __uint_as_float(ub);
                        p += vv * vv;
                    }
#pragma unroll
                    for (int off = 1; off < 16; off <<= 1) p += __shfl_xor(p, off);
                    if (n15 == 0)
                        atomicAdd(&rn[rt * 16 + quad * 4 + r], p);
                }
            __syncthreads();
            if (t < 64) {
                int gr2 = m0 + t;
                if (gr2 < M) {
                    size_t ro2 = (size_t)gr2 * rowMul + (size_t)z * zRowAdd;
                    tinvOut[ro2] = 1.f / fmaxf(sqrtf(rn[t]), 1e-8f);
                }
            }
        }
    }
}

// ---------------------------------------------------------------------------
// edge counting sort by dst; esorted = (src, dst) pairs in dst order
// ---------------------------------------------------------------------------
__global__ void ehist_kernel(const int* __restrict__ dst, int* __restrict__ ecnt, int E)
{
    for (int e = blockIdx.x * blockDim.x + threadIdx.x; e < E;
         e += gridDim.x * blockDim.x)
        atomicAdd(ecnt + dst[e], 1);
}

__global__ void escatter_kernel(const int* __restrict__ src, const int* __restrict__ dst,
                                const int* __restrict__ eptr, int* __restrict__ efill,
                                uint2* __restrict__ esorted, int E)
{
    for (int e = blockIdx.x * blockDim.x + threadIdx.x; e < E;
         e += gridDim.x * blockDim.x) {
        int d = dst[e];
        int pos = eptr[d] + atomicAdd(efill + d, 1);
        esorted[pos] = make_uint2((uint32)src[e], (uint32)d);
    }
}

// ---------------------------------------------------------------------------
// sim: MFMA diagonal over 16 sorted edges/wave; planar tr (replica planes
// Nn*D apart). All 8 A-fragments preloaded for burst issue.
// ---------------------------------------------------------------------------
__global__ __launch_bounds__(256)
void sim4_kernel(const uint2* __restrict__ esorted,
                 const unsigned short* __restrict__ featb,
                 const unsigned short* __restrict__ tr, const float* __restrict__ tinv,
                 int* __restrict__ bestS, int E, int Nn)
{
    int w = threadIdx.x >> 6, lane = threadIdx.x & 63;
    int n15 = lane & 15, quad = lane >> 4;
    int base = (blockIdx.x * 4 + w) * 16;
    if (base >= E) return;
    int ei = min(base + n15, E - 1);
    uint2 se = esorted[ei];
    const unsigned short* arow = featb + (size_t)se.x * D + quad * 8;
    const unsigned short* brow = tr + (size_t)se.y * D + quad * 8;
    size_t rstride = (size_t)Nn * D;

    s16x8 a[8];
#pragma unroll
    for (int ks = 0; ks < 8; ks++) a[ks] = *(const s16x8*)(arow + ks * 32);

    f32x4 a0 = {0.f, 0.f, 0.f, 0.f}, a1 = a0, a2 = a0, a3 = a0;
#pragma unroll
    for (int ks = 0; ks < 8; ks++) {
        s16x8 b0 = *(const s16x8*)(brow + ks * 32);
        a0 = __builtin_amdgcn_mfma_f32_16x16x32_bf16(a[ks], b0, a0, 0, 0, 0);
    }
#pragma unroll
    for (int ks = 0; ks < 8; ks++) {
        s16x8 b1 = *(const s16x8*)(brow + rstride + ks * 32);
        a1 = __builtin_amdgcn_mfma_f32_16x16x32_bf16(a[ks], b1, a1, 0, 0, 0);
    }
#pragma unroll
    for (int ks = 0; ks < 8; ks++) {
        s16x8 b2 = *(const s16x8*)(brow + 2 * rstride + ks * 32);
        a2 = __builtin_amdgcn_mfma_f32_16x16x32_bf16(a[ks], b2, a2, 0, 0, 0);
    }
#pragma unroll
    for (int ks = 0; ks < 8; ks++) {
        s16x8 b3 = *(const s16x8*)(brow + 3 * rstride + ks * 32);
        a3 = __builtin_amdgcn_mfma_f32_16x16x32_bf16(a[ks], b3, a3, 0, 0, 0);
    }

    if (quad == (n15 >> 2) && base + n15 < E) {
        int r = n15 & 3;
        int d = (int)se.y;
        float v0 = a0[r] * tinv[d];
        float v1 = a1[r] * tinv[Nn + d];
        float v2 = a2[r] * tinv[2 * Nn + d];
        float v3 = a3[r] * tinv[3 * Nn + d];
        float bv = v0; int bi = 0;
        if (v1 > bv) { bv = v1; bi = 1; }   // strict >: first-index ties
        if (v2 > bv) { bv = v2; bi = 2; }
        if (v3 > bv) { bv = v3; bi = 3; }
        bestS[base + n15] = bi;
    }
}

// ---------------------------------------------------------------------------
// unified edge list over SORTED edges (degree histogram only)
// ---------------------------------------------------------------------------
__device__ __forceinline__ void decode_edge(int e, const uint2* __restrict__ esorted,
                                            const int* __restrict__ bestS,
                                            int E, int Nn, int& s, int& d, bool& keep)
{
    if (e < E) {
        uint2 se = esorted[e];
        s = (int)se.x; d = (int)se.y; keep = (s != d);
    } else if (e < 2 * E) {
        int k = e - E;
        uint2 se = esorted[k];
        s = (int)se.x; d = (int)se.y + bestS[k] * Nn; keep = (s != d);
    } else if (e < 2 * E + T * Nn) {
        int k = e - 2 * E; int i = k / Nn; int n = k - i * Nn;
        s = n; d = n + i * Nn; keep = (i != 0);
    } else {
        int v = e - (2 * E + T * Nn); s = v; d = v; keep = true;
    }
}

__global__ void hist_kernel(const uint2* __restrict__ esorted, const int* __restrict__ bestS,
                            int* __restrict__ cnt, int E, int Nn)
{
    int total = 2 * E + (2 * T + 1) * Nn;
    for (int e = blockIdx.x * blockDim.x + threadIdx.x; e < total;
         e += gridDim.x * blockDim.x) {
        int s, d; bool keep;
        decode_edge(e, esorted, bestS, E, Nn, s, d, keep);
        if (keep) atomicAdd(cnt + d, 1);
    }
}

// ---------------------------------------------------------------------------
// merged: dinv for all rows + per-edge packed meta (src | best<<27, dinv[src])
// ---------------------------------------------------------------------------
__global__ void emeta_dinv_kernel(const uint2* __restrict__ esorted,
                                  const int* __restrict__ bestS,
                                  const int* __restrict__ cnt,
                                  float* __restrict__ dinv, uint2* __restrict__ emeta,
                                  int E, int n_total, int work)
{
    for (int i = blockIdx.x * blockDim.x + threadIdx.x; i < work;
         i += gridDim.x * blockDim.x) {
        if (i < n_total) {
            int c = cnt[i];
            dinv[i] = (c > 0) ? rsqrtf((float)c) : 0.f;
        }
        if (i < E) {
            uint2 se = esorted[i];
            uint32 packed = se.x | ((uint32)bestS[i] << 27);
            float dv = rsqrtf((float)cnt[se.x]);
            emeta[i] = make_uint2(packed, __float_as_uint(dv));
        }
    }
}

__global__ void scan_sums(const int* __restrict__ cnt, int* __restrict__ aux, int n)
{
    __shared__ int sd[256];
    int idx = blockIdx.x * 256 + threadIdx.x;
    sd[threadIdx.x] = (idx < n) ? cnt[idx] : 0;
    __syncthreads();
    for (int off = 128; off; off >>= 1) {
        if (threadIdx.x < off) sd[threadIdx.x] += sd[threadIdx.x + off];
        __syncthreads();
    }
    if (threadIdx.x == 0) aux[blockIdx.x] = sd[0];
}

__global__ void scan_aux(const int* __restrict__ aux, int* __restrict__ auxex, int nb)
{
    __shared__ int sd[1024];
    int t = threadIdx.x;
    int v = (t < nb) ? aux[t] : 0;
    sd[t] = v;
    __syncthreads();
    for (int off = 1; off < 1024; off <<= 1) {
        int x = (t >= off) ? sd[t - off] : 0;
        __syncthreads();
        sd[t] += x;
        __syncthreads();
    }
    if (t < nb) auxex[t] = sd[t] - v;
}

__global__ void scan_write(const int* __restrict__ cnt, const int* __restrict__ auxex,
                           int* __restrict__ rowptr, int n)
{
    __shared__ int sd[256];
    int t = threadIdx.x;
    int idx = blockIdx.x * 256 + t;
    int v = (idx < n) ? cnt[idx] : 0;
    sd[t] = v;
    __syncthreads();
    for (int off = 1; off < 256; off <<= 1) {
        int x = (t >= off) ? sd[t - off] : 0;
        __syncthreads();
        sd[t] += x;
        __syncthreads();
    }
    if (idx < n) {
        int rp = auxex[blockIdx.x] + sd[t] - v;
        rowptr[idx] = rp;
        if (idx == n - 1) rowptr[n] = rp + v;
    }
}

// ---------------------------------------------------------------------------
// agg5: one wave per BASE node v, produces all 5 output rows {v, v+iN}.
// xb replica row for node v, replica i: v*xrm + i*xra
// ---------------------------------------------------------------------------
__global__ __launch_bounds__(256)
void agg5_kernel(const int* __restrict__ eptr, const uint2* __restrict__ emeta,
                 const unsigned short* __restrict__ xa,
                 const unsigned short* __restrict__ xb,
                 const float* __restrict__ dinv,
                 unsigned short* __restrict__ outb, int Nn, int xrm, int xra)
{
    int wave = threadIdx.x >> 6, lane = threadIdx.x & 63;
    int v = blockIdx.x * 4 + wave;
    if (v >= Nn) return;

    float dv  = dinv[v];
    float dr1 = dinv[v + Nn];
    float dr2 = dinv[v + 2 * Nn];
    float dr3 = dinv[v + 3 * Nn];
    float dr4 = dinv[v + 4 * Nn];

    uint2 qv = *(const uint2*)(xa + (size_t)v * D + lane * 4);
    qv.x = relu2(qv.x); qv.y = relu2(qv.y);
    float y0 = bflo(qv.x), y1 = bfhi(qv.x), y2 = bflo(qv.y), y3 = bfhi(qv.y);

    float wsb = dv * dv;
    float b0 = wsb * y0, b1 = wsb * y1, b2 = wsb * y2, b3 = wsb * y3;

    float wi1 = dv * dr1, wi2 = dv * dr2, wi3 = dv * dr3;
    float r10 = wi1 * y0, r11 = wi1 * y1, r12 = wi1 * y2, r13 = wi1 * y3;
    float r20 = wi2 * y0, r21 = wi2 * y1, r22 = wi2 * y2, r23 = wi2 * y3;
    float r30 = wi3 * y0, r31 = wi3 * y1, r32 = wi3 * y2, r33 = wi3 * y3;
    float r40 = 0.f, r41 = 0.f, r42 = 0.f, r43 = 0.f;

    {
        uint2 q = *(const uint2*)(xb + ((size_t)v * xrm + 0 * (size_t)xra) * D + lane * 4);
        q.x = relu2(q.x); q.y = relu2(q.y);
        float ws = dr1 * dr1;
        r10 = fmaf(ws, bflo(q.x), r10); r11 = fmaf(ws, bfhi(q.x), r11);
        r12 = fmaf(ws, bflo(q.y), r12); r13 = fmaf(ws, bfhi(q.y), r13);
    }
    {
        uint2 q = *(const uint2*)(xb + ((size_t)v * xrm + 1 * (size_t)xra) * D + lane * 4);
        q.x = relu2(q.x); q.y = relu2(q.y);
        float ws = dr2 * dr2;
        r20 = fmaf(ws, bflo(q.x), r20); r21 = fmaf(ws, bfhi(q.x), r21);
        r22 = fmaf(ws, bflo(q.y), r22); r23 = fmaf(ws, bfhi(q.y), r23);
    }
    {
        uint2 q = *(const uint2*)(xb + ((size_t)v * xrm + 2 * (size_t)xra) * D + lane * 4);
        q.x = relu2(q.x); q.y = relu2(q.y);
        float ws = dr3 * dr3;
        r30 = fmaf(ws, bflo(q.x), r30); r31 = fmaf(ws, bfhi(q.x), r31);
        r32 = fmaf(ws, bflo(q.y), r32); r33 = fmaf(ws, bfhi(q.y), r33);
    }
    {
        uint2 q = *(const uint2*)(xb + ((size_t)v * xrm + 3 * (size_t)xra) * D + lane * 4);
        q.x = relu2(q.x); q.y = relu2(q.y);
        float ws = dr4 * dr4;
        r40 = fmaf(ws, bflo(q.x), r40); r41 = fmaf(ws, bfhi(q.x), r41);
        r42 = fmaf(ws, bflo(q.y), r42); r43 = fmaf(ws, bfhi(q.y), r43);
    }

    int j = eptr[v], jend = eptr[v + 1];

#define EDGE_META(mm, ssu, wws)                                                    \
    uint32 ssu = (uint32)__builtin_amdgcn_readfirstlane((int)mm.x);                \
    float wws = __uint_as_float((uint32)__builtin_amdgcn_readfirstlane((int)mm.y));

#define EDGE_BODY(qq, ss, bb, ww)                                                  \
    {                                                                              \
        float x0 = bflo(qq.x), x1 = bfhi(qq.x), x2 = bflo(qq.y), x3 = bfhi(qq.y);  \
        float wb = (ss != v) ? (ww) * dv : 0.f;                                    \
        if (bb == 0) wb += wb;                                                     \
        b0 = fmaf(wb, x0, b0); b1 = fmaf(wb, x1, b1);                              \
        b2 = fmaf(wb, x2, b2); b3 = fmaf(wb, x3, b3);                              \
        if (bb == 1) {                                                             \
            float wr = (ww) * dr1;                                                 \
            r10 = fmaf(wr, x0, r10); r11 = fmaf(wr, x1, r11);                      \
            r12 = fmaf(wr, x2, r12); r13 = fmaf(wr, x3, r13);                      \
        } else if (bb == 2) {                                                      \
            float wr = (ww) * dr2;                                                 \
            r20 = fmaf(wr, x0, r20); r21 = fmaf(wr, x1, r21);                      \
            r22 = fmaf(wr, x2, r22); r23 = fmaf(wr, x3, r23);                      \
        } else if (bb == 3) {                                                      \
            float wr = (ww) * dr3;                                                 \
            r30 = fmaf(wr, x0, r30); r31 = fmaf(wr, x1, r31);                      \
            r32 = fmaf(wr, x2, r32); r33 = fmaf(wr, x3, r33);                      \
        }                                                                          \
    }

    for (; j + 4 <= jend; j += 4) {
        uint2 m0 = emeta[j];
        uint2 m1 = emeta[j + 1];
        uint2 m2 = emeta[j + 2];
        uint2 m3 = emeta[j + 3];
        EDGE_META(m0, su0, ws0); EDGE_META(m1, su1, ws1);
        EDGE_META(m2, su2, ws2); EDGE_META(m3, su3, ws3);
        int s0 = (int)(su0 & 0x07FFFFFFu), bx0 = (int)(su0 >> 27);
        int s1 = (int)(su1 & 0x07FFFFFFu), bx1 = (int)(su1 >> 27);
        int s2 = (int)(su2 & 0x07FFFFFFu), bx2 = (int)(su2 >> 27);
        int s3 = (int)(su3 & 0x07FFFFFFu), bx3 = (int)(su3 >> 27);
        uint2 q0 = *(const uint2*)(xa + (size_t)s0 * D + lane * 4);
        uint2 q1 = *(const uint2*)(xa + (size_t)s1 * D + lane * 4);
        uint2 q2 = *(const uint2*)(xa + (size_t)s2 * D + lane * 4);
        uint2 q3 = *(const uint2*)(xa + (size_t)s3 * D + lane * 4);
        q0.x = relu2(q0.x); q0.y = relu2(q0.y);
        q1.x = relu2(q1.x); q1.y = relu2(q1.y);
        q2.x = relu2(q2.x); q2.y = relu2(q2.y);
        q3.x = relu2(q3.x); q3.y = relu2(q3.y);
        EDGE_BODY(q0, s0, bx0, ws0);
        EDGE_BODY(q1, s1, bx1, ws1);
        EDGE_BODY(q2, s2, bx2, ws2);
        EDGE_BODY(q3, s3, bx3, ws3);
    }
    for (; j + 2 <= jend; j += 2) {
        uint2 m0 = emeta[j];
        uint2 m1 = emeta[j + 1];
        EDGE_META(m0, su0, ws0); EDGE_META(m1, su1, ws1);
        int s0 = (int)(su0 & 0x07FFFFFFu), bx0 = (int)(su0 >> 27);
        int s1 = (int)(su1 & 0x07FFFFFFu), bx1 = (int)(su1 >> 27);
        uint2 q0 = *(const uint2*)(xa + (size_t)s0 * D + lane * 4);
        uint2 q1 = *(const uint2*)(xa + (size_t)s1 * D + lane * 4);
        q0.x = relu2(q0.x); q0.y = relu2(q0.y);
        q1.x = relu2(q1.x); q1.y = relu2(q1.y);
        EDGE_BODY(q0, s0, bx0, ws0);
        EDGE_BODY(q1, s1, bx1, ws1);
    }
    if (j < jend) {
        uint2 m0 = emeta[j];
        EDGE_META(m0, su0, ws0);
        int s0 = (int)(su0 & 0x07FFFFFFu), bx0 = (int)(su0 >> 27);
        uint2 q0 = *(const uint2*)(xa + (size_t)s0 * D + lane * 4);
        q0.x = relu2(q0.x); q0.y = relu2(q0.y);
        EDGE_BODY(q0, s0, bx0, ws0);
    }
#undef EDGE_BODY
#undef EDGE_META

    uint2 o;
    o.x = pack2(b0, b1); o.y = pack2(b2, b3);
    *(uint2*)(outb + (size_t)v * D + lane * 4) = o;
    o.x = pack2(r10, r11); o.y = pack2(r12, r13);
    *(uint2*)(outb + ((size_t)v + Nn) * D + lane * 4) = o;
    o.x = pack2(r20, r21); o.y = pack2(r22, r23);
    *(uint2*)(outb + ((size_t)v + 2 * (size_t)Nn) * D + lane * 4) = o;
    o.x = pack2(r30, r31); o.y = pack2(r32, r33);
    *(uint2*)(outb + ((size_t)v + 3 * (size_t)Nn) * D + lane * 4) = o;
    o.x = pack2(r40, r41); o.y = pack2(r42, r43);
    *(uint2*)(outb + ((size_t)v + 4 * (size_t)Nn) * D + lane * 4) = o;
}

// ---------------------------------------------------------------------------
// MFMA logits + fused argmax + H. A-staging via global_load_lds with the
// gemm swizzle; relu applied to the fragment AFTER the LDS read (elementwise,
// same numerics). Reads R2 with tail over-read into BigB slack; H writes
// gr<M guarded.
// ---------------------------------------------------------------------------
__global__ __launch_bounds__(256, 2)
void logits_mfma(const unsigned short* __restrict__ af2, const float* __restrict__ Wl,
                 const float* __restrict__ bl, float* __restrict__ H,
                 int M, int Nn, int nStripes)
{
    __shared__ unsigned short Asm[64 * 256];
    int t = threadIdx.x, w = t >> 6, lane = t & 63;
    int n15 = lane & 15, quad = lane >> 4;

    s16x8 bfr[4][8];
#pragma unroll
    for (int nt = 0; nt < 4; nt++)
#pragma unroll
        for (int ks = 0; ks < 8; ks++) {
            s16x8 f;
#pragma unroll
            for (int j = 0; j < 8; j++) {
                int k = ks * 32 + quad * 8 + j;
                f[j] = (short)f2bf(Wl[(size_t)k * NS + nt * 16 + n15]);
            }
            bfr[nt][ks] = f;
        }
    float bcol[4];
#pragma unroll
    for (int nt = 0; nt < 4; nt++) bcol[nt] = bl[nt * 16 + n15];

    for (int s = blockIdx.x; s < nStripes; s += gridDim.x) {
        int m0 = s * 64;
        __syncthreads();
#pragma unroll
        for (int i = 0; i < 8; i++) {
            int idx = i * 256 + t;
            int row = idx >> 5, unit = idx & 31;
            const unsigned short* gp = af2 + (size_t)(m0 + row) * 256
                                       + ((unit ^ (row & 7)) << 3);
            __builtin_amdgcn_global_load_lds(
                (const __attribute__((address_space(1))) void*)gp,
                (__attribute__((address_space(3))) void*)(Asm + ((i * 256 + w * 64) << 3)),
                16, 0, 0);
        }
        __syncthreads();

        f32x4 acc[4];
#pragma unroll
        for (int nt = 0; nt < 4; nt++)
#pragma unroll
            for (int e = 0; e < 4; e++) acc[nt][e] = 0.f;

        int row = w * 16 + n15;
        int rbase = row * 256;
        int rx = row & 7;
#pragma unroll
        for (int ks = 0; ks < 8; ks++) {
            int unit = quad + ks * 4;
            s16x8 a = relu8(*(const s16x8*)(Asm + rbase + ((unit ^ rx) << 3)));
#pragma unroll
            for (int nt = 0; nt < 4; nt++)
                acc[nt] = __builtin_amdgcn_mfma_f32_16x16x32_bf16(
                    a, bfr[nt][ks], acc[nt], 0, 0, 0);
        }

#pragma unroll
        for (int e = 0; e < 4; e++) {
            float bv = acc[0][e] + bcol[0]; int bi = n15;
#pragma unroll
            for (int nt = 1; nt < 4; nt++) {
                float v = acc[nt][e] + bcol[nt];
                int c = nt * 16 + n15;
                if (v > bv) { bv = v; bi = c; }
            }
#pragma unroll
            for (int off = 1; off < 16; off <<= 1) {
                float ov = __shfl_xor(bv, off);
                int   oi = __shfl_xor(bi, off);
                if (ov > bv || (ov == bv && oi < bi)) { bv = ov; bi = oi; }
            }
            if (n15 == 0) {
                int gr = m0 + w * 16 + quad * 4 + e;
                if (gr < M) atomicAdd(H + (size_t)(gr % Nn) * NS + bi, 1.0f);
            }
        }
    }
}

// ---------------------------------------------------------------------------
// maskTb: H (Nn x NS fp32) -> bf16 maskT [NS][Kpad] (1.0 where H>0, else 0),
// zero-padded in [Nn, Kpad). LDS-tiled transpose, coalesced both sides.
// ---------------------------------------------------------------------------
__global__ __launch_bounds__(256)
void maskTb_kernel(const float* __restrict__ H, unsigned short* __restrict__ maskTb,
                   int Nn, int Kpad)
{
    __shared__ unsigned short tile[64 * 72];   // [c][n], pad 72
    int t = threadIdx.x;
    int n0 = blockIdx.x * 64;
    int c = t & 63, rr = t >> 6;
#pragma unroll
    for (int i = 0; i < 16; i++) {
        int n = rr + i * 4;
        float hv = (n0 + n < Nn) ? H[(size_t)(n0 + n) * NS + c] : 0.f;
        tile[c * 72 + n] = (hv > 0.f) ? (unsigned short)0x3F80 : (unsigned short)0;
    }
    __syncthreads();
#pragma unroll
    for (int i = 0; i < 2; i++) {
        int idx = i * 256 + t;              // 0..511: 64 rows x 8 chunks
        int cc = idx >> 3, ch = idx & 7;
        uint4 v = *(const uint4*)(tile + cc * 72 + ch * 8);
        *(uint4*)(maskTb + (size_t)cc * Kpad + n0 + ch * 8) = v;
    }
}

// ---------------------------------------------------------------------------
// he_gemm: he = maskTb (64 x Kpad bf16) @ af2 (Kpad x 256 bf16), split-K.
// ---------------------------------------------------------------------------
__global__ __launch_bounds__(256, 2)
void he_gemm(const unsigned short* __restrict__ maskTb,
             const unsigned short* __restrict__ af2,
             float* __restrict__ partials, int Kpad)
{
    __shared__ unsigned short Bsm[32 * 264];
    int t = threadIdx.x, w = t >> 6, lane = t & 63;
    int n15 = lane & 15, quad = lane >> 4;
    int k0 = blockIdx.x * 256;

    f32x4 acc[4][4];
#pragma unroll
    for (int mt = 0; mt < 4; mt++)
#pragma unroll
        for (int nt = 0; nt < 4; nt++)
#pragma unroll
            for (int e = 0; e < 4; e++) acc[mt][nt][e] = 0.f;

    for (int s = 0; s < 8; s++) {
        int k = k0 + s * 32;
        __syncthreads();
#pragma unroll
        for (int i = 0; i < 4; i++) {
            int idx = i * 256 + t;              // 0..1023: 32 rows x 32 chunks
            int row = idx >> 5, col8 = (idx & 31) * 8;
            uint4 v = *(const uint4*)(af2 + (size_t)(k + row) * 256 + col8);
            *(uint4*)(Bsm + row * 264 + col8) = v;
        }
        __syncthreads();

        s16x8 a[4];
#pragma unroll
        for (int mt = 0; mt < 4; mt++)
            a[mt] = *(const s16x8*)(maskTb + (size_t)(mt * 16 + n15) * Kpad
                                    + k + quad * 8);
#pragma unroll
        for (int nt = 0; nt < 4; nt++) {
            int ncol = w * 64 + nt * 16 + n15;
            s16x8 b;
#pragma unroll
            for (int j = 0; j < 8; j++)
                b[j] = (short)Bsm[(quad * 8 + j) * 264 + ncol];
#pragma unroll
            for (int mt = 0; mt < 4; mt++)
                acc[mt][nt] = __builtin_amdgcn_mfma_f32_16x16x32_bf16(
                    a[mt], b, acc[mt][nt], 0, 0, 0);
        }
    }

    float* pdst = partials + (size_t)blockIdx.x * (64 * 256);
#pragma unroll
    for (int mt = 0; mt < 4; mt++)
#pragma unroll
        for (int nt = 0; nt < 4; nt++)
#pragma unroll
            for (int r = 0; r < 4; r++) {
                int m = mt * 16 + quad * 4 + r;
                int n = w * 64 + nt * 16 + n15;
                pdst[(size_t)m * 256 + n] = acc[mt][nt][r];
            }
}

// ---------------------------------------------------------------------------
// he_reduce2: out_he[c][f] = sum_b partials[b][c][f]  (plain store)
// ---------------------------------------------------------------------------
__global__ __launch_bounds__(256)
void he_reduce2(const float* __restrict__ partials, float* __restrict__ he, int KB)
{
    int idx = blockIdx.x * 256 + threadIdx.x;   // 0..16383
    float s = 0.f;
    for (int b = 0; b < KB; b++)
        s += partials[(size_t)b * 16384 + idx];
    he[idx] = s;
}

// ---------------------------------------------------------------------------
__global__ void bigb_copy(const float* __restrict__ he, float* __restrict__ BigB)
{
    int idx = blockIdx.x * 256 + threadIdx.x;
    if (idx < D * NS) {
        int d = idx >> 6, c = idx & 63;
        BigB[idx] = he[(size_t)c * D + d];
    }
}

__global__ __launch_bounds__(256)
void bigb_mm(const float* __restrict__ lin_w, const float* __restrict__ lin_b,
             const float* __restrict__ he, float* __restrict__ BigB,
             float* __restrict__ beta)
{
    int gw = (int)((blockIdx.x * 256 + threadIdx.x) >> 6);
    int lane = threadIdx.x & 63;
    const int totalA = T * D * NS;
    if (gw >= totalA + T * NS) return;
    const float* xrow; const float* hrow; float* outp;
    if (gw < totalA) {
        int t = gw / (D * NS); int rem = gw - t * D * NS;
        int d = rem / NS; int c = rem - d * NS;
        xrow = lin_w + ((size_t)t * D + d) * D;
        hrow = he + (size_t)c * D;
        outp = BigB + ((size_t)(t + 1) * D + d) * NS + c;
    } else {
        int i = gw - totalA; int t = i / NS; int c = i - t * NS;
        xrow = lin_b + (size_t)t * D;
        hrow = he + (size_t)c * D;
        outp = beta + (size_t)(t + 1) * NS + c;
    }
    float4 x = *(const float4*)(xrow + lane * 4);
    float4 h = *(const float4*)(hrow + lane * 4);
    float s = x.x * h.x + x.y * h.y + x.z * h.z + x.w * h.w;
#pragma unroll
    for (int off = 32; off; off >>= 1) s += __shfl_xor(s, off);
    if (lane == 0) *outp = s;
}

// ---------------------------------------------------------------------------
// MFMA dots: useBf=1 -> global_load_lds from featb (swizzled, +slack);
// useBf=0 -> guarded fp32 VGPR staging into the SAME swizzled layout.
// grid (nBlk, 5)
// ---------------------------------------------------------------------------
__global__ __launch_bounds__(256, 2)
void dots_mfma(const unsigned short* __restrict__ featb,
               const float* __restrict__ feat32, int useBf,
               const float* __restrict__ BigB,
               const float* __restrict__ beta, float* __restrict__ dots,
               int Nn, int nStripes)
{
    __shared__ unsigned short Asm[64 * 256];
    int t = threadIdx.x, w = t >> 6, lane = t & 63;
    int n15 = lane & 15, quad = lane >> 4;
    int rho = blockIdx.y;
    const float* Bp = BigB + (size_t)rho * D * NS;

    s16x8 bfr[4][8];
#pragma unroll
    for (int nt = 0; nt < 4; nt++)
#pragma unroll
        for (int ks = 0; ks < 8; ks++) {
            s16x8 f;
#pragma unroll
            for (int j = 0; j < 8; j++) {
                int k = ks * 32 + quad * 8 + j;
                f[j] = (short)f2bf(Bp[(size_t)k * NS + nt * 16 + n15]);
            }
            bfr[nt][ks] = f;
        }
    float bcol[4];
#pragma unroll
    for (int nt = 0; nt < 4; nt++) bcol[nt] = beta[rho * NS + nt * 16 + n15];

    for (int s = blockIdx.x; s < nStripes; s += gridDim.x) {
        int m0 = s * 64;
        __syncthreads();
        if (useBf) {
#pragma unroll
            for (int i = 0; i < 8; i++) {
                int idx = i * 256 + t;
                int row = idx >> 5, unit = idx & 31;
                const unsigned short* gp = featb + (size_t)(m0 + row) * 256
                                           + ((unit ^ (row & 7)) << 3);
                __builtin_amdgcn_global_load_lds(
                    (const __attribute__((address_space(1))) void*)gp,
                    (__attribute__((address_space(3))) void*)(Asm + ((i * 256 + w * 64) << 3)),
                    16, 0, 0);
            }
        } else {
#pragma unroll
            for (int i = 0; i < 8; i++) {
                int idx = i * 256 + t;
                int m = idx >> 5, unit = idx & 31;
                int gm = m0 + m;
                uint4 o = make_uint4(0u, 0u, 0u, 0u);
                if (gm < Nn) {
                    int kc = unit * 8;
                    float4 a = *(const float4*)(feat32 + (size_t)gm * 256 + kc);
                    float4 b = *(const float4*)(feat32 + (size_t)gm * 256 + kc + 4);
                    o.x = pack2(a.x, a.y); o.y = pack2(a.z, a.w);
                    o.z = pack2(b.x, b.y); o.w = pack2(b.z, b.w);
                }
                *(uint4*)(Asm + m * 256 + ((unit ^ (m & 7)) << 3)) = o;
            }
        }
        __syncthreads();

        f32x4 acc[4];
#pragma unroll
        for (int nt = 0; nt < 4; nt++)
#pragma unroll
            for (int e = 0; e < 4; e++) acc[nt][e] = 0.f;

        int row = w * 16 + n15;
        int rbase = row * 256;
        int rx = row & 7;
#pragma unroll
        for (int ks = 0; ks < 8; ks++) {
            int unit = quad + ks * 4;
            s16x8 a = *(const s16x8*)(Asm + rbase + ((unit ^ rx) << 3));
#pragma unroll
            for (int nt = 0; nt < 4; nt++)
                acc[nt] = __builtin_amdgcn_mfma_f32_16x16x32_bf16(
                    a, bfr[nt][ks], acc[nt], 0, 0, 0);
        }

#pragma unroll
        for (int e = 0; e < 4; e++) {
            int gr = m0 + w * 16 + quad * 4 + e;
            if (gr >= Nn) continue;
#pragma unroll
            for (int nt = 0; nt < 4; nt++) {
                int c = nt * 16 + n15;
                dots[((size_t)rho * Nn + gr) * NS + c] = (acc[nt][e] + bcol[nt]) * 0.0625f;
            }
        }
    }
}

// ---------------------------------------------------------------------------
extern "C" void kernel_launch(void* const* d_in, const int* in_sizes, int n_in,
                              void* d_out, int out_size, void* d_ws, size_t ws_size,
                              hipStream_t stream)
{
    const int*   edge_index = (const int*)d_in[0];
    const float* features   = (const float*)d_in[1];
    const float* lin_w      = (const float*)d_in[2];
    const float* lin_b      = (const float*)d_in[3];
    const float* gcn0_w     = (const float*)d_in[4];
    const float* gcn0_b     = (const float*)d_in[5];
    const float* gcn1_w     = (const float*)d_in[6];
    const float* gcn1_b     = (const float*)d_in[7];
    const float* lin1_w     = (const float*)d_in[8];
    const float* lin1_b     = (const float*)d_in[9];

    int E  = in_sizes[0] / 2;
    int Nn = in_sizes[1] / D;
    int n_total = (T + 1) * Nn;
    int Mrep = T * Nn;

    const int* src = edge_index;
    const int* dst = edge_index + E;

    float* out_H    = (float*)d_out;
    float* out_he   = out_H + (size_t)Nn * NS;
    float* out_dots = out_he + (size_t)NS * D;

    // he GEMM split-K geometry
    int KB   = (Nn + 255) / 256;      // blocks, 256 K per block
    int Kpad = KB * 256;

    // ---- ws carve: two big bf16 regions + BigB (+ featb if it fits)
    char* ws0 = (char*)d_ws;
    char* wsp = ws0;
    auto carve = [&](size_t bytes) {
        char* p = wsp; wsp += (bytes + 255) & ~(size_t)255; return p;
    };
    unsigned short* R1   = (unsigned short*)carve((size_t)n_total * D * 2);
    unsigned short* R2   = (unsigned short*)carve((size_t)n_total * D * 2);
    float*          BigB = (float*)carve((size_t)(T + 1) * D * NS * 4);
    float*          beta = (float*)carve((size_t)(T + 1) * NS * 4);
    unsigned short* transformed = R2;   // planar prefix of R2 (T*Nn rows)

    // featb: prefer ws (safe to read during dots_mfma); fall back to the
    // out_dots scratch region + fp32 staging in dots_mfma. +32KB slack for
    // gemm tail-stripe over-read (global_load_lds reads past M).
    size_t featb_bytes = (size_t)Nn * D * 2 + 64 * 512;
    unsigned short* featb = nullptr;
    int useBfDots = 0;
    if ((size_t)(wsp - ws0) + featb_bytes + 256 <= ws_size) {
        featb = (unsigned short*)carve(featb_bytes);
        useBfDots = 1;
    }

    // ---- scratch in the out_dots region (dead before dots_mfma)
    char* sc = (char*)out_dots;
    auto carve2 = [&](size_t bytes) {
        char* p = sc; sc += (bytes + 255) & ~(size_t)255; return p;
    };
    float* tinv    = (float*)carve2((size_t)Mrep * 4);
    int*   best    = (int*)carve2((size_t)E * 4);       // SORTED order
    // cnt / ecnt / efill contiguous -> single zero launch
    int*   cnt     = (int*)carve2((size_t)(n_total + 2 * Nn) * 4);
    int*   ecnt    = cnt + n_total;
    int*   efill   = ecnt + Nn;
    float* dinv    = (float*)carve2((size_t)n_total * 4);
    int*   aux     = (int*)carve2(1024 * 4);
    int*   auxex   = (int*)carve2(1024 * 4);
    if (!featb) featb = (unsigned short*)carve2(featb_bytes);
    unsigned short* Wfrags = (unsigned short*)carve2((size_t)6 * 65536 * 2);
    int*   eptr    = (int*)carve2((size_t)(Nn + 1) * 4);
    uint2* esorted = (uint2*)carve2((size_t)E * 8);     // (src, dst) in dst order
    uint2* emeta   = (uint2*)carve2((size_t)E * 8);     // (src|best<<27, dinv[src])
    unsigned short* maskTb = (unsigned short*)carve2((size_t)NS * Kpad * 2);

    // he_gemm partials live in R1 (dead after layer-1 agg): KB*64KB ~ 12.8MB
    float* partials = (float*)R1;

    // ---- zero accumulators (merged: cnt+ecnt+efill in one shot)
    zero_kernel<<<512, 256, 0, stream>>>((uint32*)cnt, (long long)(n_total + 2 * Nn));
    zero_kernel<<<512, 256, 0, stream>>>((uint32*)out_H, (long long)Nn * NS + NS * D);
    zero_kernel<<<1, 256, 0, stream>>>((uint32*)beta, (T + 1) * NS);

    // 0. conversions
    wfrag_kernel<<<dim3(256, 6), 256, 0, stream>>>(gcn0_w, gcn1_w, lin_w, Wfrags);
    f2bf_kernel<<<2048, 256, 0, stream>>>(features, featb, (long long)Nn * D / 8);

    // 1. transformed[z*Nn + n] = featb[n] @ lin_w[z] + lin_b[z], fused row norms
    int strN = (Nn + 63) / 64;
    gemm_mfma<<<dim3(512, T), 256, 0, stream>>>(featb, Wfrags + 2 * 65536, lin_b,
                                                transformed, Nn, strN, 1, Nn, tinv);

    // 2. edge sort by dst + MFMA-diagonal sim
    ehist_kernel<<<2048, 256, 0, stream>>>(dst, ecnt, E);
    int enb = (Nn + 255) / 256;
    scan_sums<<<enb, 256, 0, stream>>>(ecnt, aux, Nn);
    scan_aux<<<1, 1024, 0, stream>>>(aux, auxex, enb);
    scan_write<<<enb, 256, 0, stream>>>(ecnt, auxex, eptr, Nn);
    escatter_kernel<<<2048, 256, 0, stream>>>(src, dst, eptr, efill, esorted, E);
    int nGroups = (E + 15) / 16;
    sim4_kernel<<<(nGroups + 3) / 4, 256, 0, stream>>>(esorted, featb, transformed,
                                                       tinv, best, E, Nn);

    // 3. degrees -> dinv + packed per-edge meta (merged)
    hist_kernel<<<2048, 256, 0, stream>>>(esorted, best, cnt, E, Nn);
    int work = (E > n_total) ? E : n_total;
    emeta_dinv_kernel<<<2048, 256, 0, stream>>>(esorted, best, cnt, dinv, emeta,
                                                E, n_total, work);

    // 4. layer 0 (xb = transformed, planar replica planes)
    int strT = (n_total + 63) / 64;
    agg5_kernel<<<(Nn + 3) / 4, 256, 0, stream>>>(eptr, emeta, featb, transformed,
                                                  dinv, R1, Nn, 1, Nn);
    gemm_mfma<<<dim3(512, 1), 256, 0, stream>>>(R1, Wfrags, gcn0_b, R1, n_total,
                                                strT, 1, 0, nullptr);

    // 5. layer 1 (xb = R1 planar replicas)
    agg5_kernel<<<(Nn + 3) / 4, 256, 0, stream>>>(eptr, emeta, R1, R1 + (size_t)Nn * D,
                                                  dinv, R2, Nn, 1, Nn);
    gemm_mfma<<<dim3(512, 1), 256, 0, stream>>>(R2, Wfrags + 65536, gcn1_b, R2,
                                                n_total, strT, 1, 0, nullptr);

    // 6. classes + H (MFMA + fused argmax, gload_lds staging + post-read relu)
    logits_mfma<<<512, 256, 0, stream>>>(R2, lin1_w, lin1_b, out_H, n_total, Nn, strT);

    // 7. hyperedge features as a mask GEMM: maskT build + split-K MFMA + reduce
    maskTb_kernel<<<Kpad / 64, 256, 0, stream>>>(out_H, maskTb, Nn, Kpad);
    he_gemm<<<KB, 256, 0, stream>>>(maskTb, R2, partials, Kpad);
    he_reduce2<<<64, 256, 0, stream>>>(partials, out_he, KB);

    // 8. dots (MFMA over 5 rho)
    bigb_copy<<<(D * NS + 255) / 256, 256, 0, stream>>>(out_he, BigB);
    bigb_mm<<<(T * D * NS + T * NS + 3) / 4, 256, 0, stream>>>(lin_w, lin_b, out_he,
                                                               BigB, beta);
    dots_mfma<<<dim3(160, 5), 256, 0, stream>>>(featb, features, useBfDots,
                                                BigB, beta, out_dots, Nn, strN);
}